// Round 2
// baseline (2918.059 us; speedup 1.0000x reference)
//
#include <hip/hip_runtime.h>
#include <hip/hip_bf16.h>
#include <math.h>

#define BB 128
#define CIN 256
#define COUT 512
#define TT 200
#define HH 8
#define KD 64
#define HK 512
#define HC 2048

typedef __hip_bfloat16 bf16;

// ---------------- K1: fold Wv @ Wp_h -> Wvp[h][ci][c], bvp[h][c] ----------------
__global__ __launch_bounds__(256) void k_wvp(const float* __restrict__ Wv,
    const float* __restrict__ Wp, const float* __restrict__ bv,
    float* __restrict__ Wvp, float* __restrict__ bvp) {
  __shared__ __align__(16) float wpl[32][256];
  __shared__ __align__(16) float wvl[17][32];
  int h = blockIdx.x >> 4, ci0 = (blockIdx.x & 15) << 4;
  int c = threadIdx.x;
  float acc[17];
#pragma unroll
  for (int i = 0; i < 17; ++i) acc[i] = 0.f;
  for (int p0 = 0; p0 < CIN; p0 += 32) {
    __syncthreads();
    for (int idx = c; idx < 17 * 32; idx += 256) {
      int pp = idx & 31, cil = idx >> 5;
      wvl[cil][pp] = (cil < 16) ? Wv[(size_t)(ci0 + cil) * HC + h * CIN + p0 + pp]
                                : bv[h * CIN + p0 + pp];
    }
    for (int idx = c; idx < 32 * 256; idx += 256) {
      int cc = idx & 255, pp = idx >> 8;
      wpl[pp][cc] = Wp[(size_t)(h * CIN + p0 + pp) * CIN + cc];
    }
    __syncthreads();
#pragma unroll 4
    for (int pp = 0; pp < 32; ++pp) {
      float w = wpl[pp][c];
#pragma unroll
      for (int i = 0; i < 17; ++i) acc[i] += wvl[i][pp] * w;
    }
  }
  for (int i = 0; i < 16; ++i)
    Wvp[(size_t)h * CIN * CIN + (size_t)(ci0 + i) * CIN + c] = acc[i];
  if (ci0 == 0) bvp[h * CIN + c] = acc[16];
}

// ---------------- K2: q,k projection -> bf16 ws, layout [bh][t][64] ----------------
__global__ __launch_bounds__(256) void k_qk(const float* __restrict__ x,
    const float* __restrict__ Wq, const float* __restrict__ bq,
    const float* __restrict__ Wk, const float* __restrict__ bk,
    bf16* __restrict__ qo, bf16* __restrict__ ko) {
  __shared__ __align__(16) float xl[32][32];
  __shared__ __align__(16) float wql[32][64];
  __shared__ __align__(16) float wkl[32][64];
  int bh = blockIdx.x, b = bh >> 3, h = bh & 7;
  int tid = threadIdx.x, kk = tid & 63, tg = tid >> 6;
  const float* xb = x + (size_t)b * CIN * TT;
  float biasq = bq[h * KD + kk], biask = bk[h * KD + kk];
  for (int t0 = 0; t0 < TT; t0 += 32) {
    float accq[8], acck[8];
#pragma unroll
    for (int j = 0; j < 8; ++j) { accq[j] = 0.f; acck[j] = 0.f; }
    for (int c0 = 0; c0 < CIN; c0 += 32) {
      __syncthreads();
      for (int idx = tid; idx < 32 * 32; idx += 256) {
        int t = idx & 31, cii = idx >> 5;
        xl[cii][t] = (t0 + t < TT) ? xb[(size_t)(c0 + cii) * TT + t0 + t] : 0.f;
      }
      for (int idx = tid; idx < 32 * 64; idx += 256) {
        int k2 = idx & 63, cii = idx >> 6;
        wql[cii][k2] = Wq[(size_t)(c0 + cii) * HK + h * KD + k2];
        wkl[cii][k2] = Wk[(size_t)(c0 + cii) * HK + h * KD + k2];
      }
      __syncthreads();
#pragma unroll 4
      for (int cii = 0; cii < 32; ++cii) {
        float wq = wql[cii][kk], wk = wkl[cii][kk];
        const float4* xr = (const float4*)xl[cii];
        float4 x0 = xr[tg * 2], x1 = xr[tg * 2 + 1];
        accq[0] += x0.x * wq; accq[1] += x0.y * wq; accq[2] += x0.z * wq; accq[3] += x0.w * wq;
        accq[4] += x1.x * wq; accq[5] += x1.y * wq; accq[6] += x1.z * wq; accq[7] += x1.w * wq;
        acck[0] += x0.x * wk; acck[1] += x0.y * wk; acck[2] += x0.z * wk; acck[3] += x0.w * wk;
        acck[4] += x1.x * wk; acck[5] += x1.y * wk; acck[6] += x1.z * wk; acck[7] += x1.w * wk;
      }
    }
    size_t base = (size_t)bh * TT * KD;
#pragma unroll
    for (int j = 0; j < 8; ++j) {
      int t = t0 + tg * 8 + j;
      if (t < TT) {
        qo[base + (size_t)t * KD + kk] = __float2bfloat16(accq[j] + biasq);
        ko[base + (size_t)t * KD + kk] = __float2bfloat16(acck[j] + biask);
      }
    }
  }
}

// ---------------- K3: vp[bh][s][c] = x @ Wvp_h + bvp (bf16 out) ----------------
__global__ __launch_bounds__(256) void k_vp(const float* __restrict__ x,
    const float* __restrict__ Wvp, const float* __restrict__ bvp,
    bf16* __restrict__ vp) {
  __shared__ __align__(16) float xl[32][32];
  __shared__ __align__(16) float wl[32][256];
  int bh = blockIdx.x, b = bh >> 3, h = bh & 7;
  int c = threadIdx.x;
  const float* xb = x + (size_t)b * CIN * TT;
  const float* wv = Wvp + (size_t)h * CIN * CIN;
  float bias = bvp[h * CIN + c];
  for (int s0 = 0; s0 < TT; s0 += 32) {
    float acc[32];
#pragma unroll
    for (int j = 0; j < 32; ++j) acc[j] = 0.f;
    for (int c0 = 0; c0 < CIN; c0 += 32) {
      __syncthreads();
      for (int idx = c; idx < 32 * 32; idx += 256) {
        int ss = idx & 31, cii = idx >> 5;
        xl[cii][ss] = (s0 + ss < TT) ? xb[(size_t)(c0 + cii) * TT + s0 + ss] : 0.f;
      }
      for (int idx = c; idx < 32 * 256; idx += 256) {
        int cc = idx & 255, cii = idx >> 8;
        wl[cii][cc] = wv[(size_t)(c0 + cii) * CIN + cc];
      }
      __syncthreads();
#pragma unroll 2
      for (int cii = 0; cii < 32; ++cii) {
        float w = wl[cii][c];
        const float4* xr = (const float4*)xl[cii];
#pragma unroll
        for (int j4 = 0; j4 < 8; ++j4) {
          float4 xv = xr[j4];
          acc[j4 * 4 + 0] += xv.x * w; acc[j4 * 4 + 1] += xv.y * w;
          acc[j4 * 4 + 2] += xv.z * w; acc[j4 * 4 + 3] += xv.w * w;
        }
      }
    }
    size_t base = (size_t)bh * TT * CIN;
#pragma unroll
    for (int j = 0; j < 32; ++j) {
      int s = s0 + j;
      if (s < TT) vp[base + (size_t)s * CIN + c] = __float2bfloat16(acc[j] + bias);
    }
  }
}

// ---------------- K4: per-(b,h) scores + causal softmax -> att (f32, d_out) ----------------
__global__ __launch_bounds__(512) void k_attn(const bf16* __restrict__ qo,
    const bf16* __restrict__ ko, float* __restrict__ att) {
  __shared__ __align__(16) float ql[TT][64];
  __shared__ __align__(16) float kl[TT][65];
  int bh = blockIdx.x, tid = threadIdx.x;
  const bf16* qb = qo + (size_t)bh * TT * KD;
  const bf16* kb = ko + (size_t)bh * TT * KD;
  for (int idx = tid; idx < TT * KD; idx += 512) {
    int k2 = idx & 63, t = idx >> 6;
    ql[t][k2] = __bfloat162float(qb[idx]);
    kl[t][k2] = __bfloat162float(kb[idx]);
  }
  __syncthreads();
  int lane = tid & 63, w = tid >> 6;
  float* ab = att + (size_t)bh * TT * TT;
  for (int t = w; t < TT; t += 8) {
    float val[4];
    int simax = t >> 6;
#pragma unroll
    for (int si = 0; si < 4; ++si) {
      int s = lane + (si << 6);
      if (si <= simax && s <= t) {
        float acc = 0.f;
#pragma unroll 8
        for (int ci = 0; ci < KD; ++ci) acc += ql[t][ci] * kl[s][ci];
        val[si] = acc * 0.125f;
      } else val[si] = -INFINITY;
    }
    float m = fmaxf(fmaxf(val[0], val[1]), fmaxf(val[2], val[3]));
#pragma unroll
    for (int off = 32; off; off >>= 1) m = fmaxf(m, __shfl_xor(m, off));
    float e[4], sum = 0.f;
#pragma unroll
    for (int si = 0; si < 4; ++si) {
      e[si] = (val[si] > -INFINITY) ? __expf(val[si] - m) : 0.f;
      sum += e[si];
    }
#pragma unroll
    for (int off = 32; off; off >>= 1) sum += __shfl_xor(sum, off);
    float inv = 1.f / sum;
#pragma unroll
    for (int si = 0; si < 4; ++si) {
      int s = lane + (si << 6);
      if (s < TT) ab[(size_t)t * TT + s] = e[si] * inv;
    }
  }
}

// ---------------- K5: attn_out(B,C,T) = sum_h att_h @ vp_h + bp ----------------
__global__ __launch_bounds__(512) void k_av(const float* __restrict__ att,
    const bf16* __restrict__ vp, const float* __restrict__ bp, float* __restrict__ at) {
  __shared__ __align__(16) float al[100 * 32];
  __shared__ __align__(16) float vl[32][256];
  int blk = blockIdx.x, b = blk >> 1, half = blk & 1;
  int tid = threadIdx.x;
  int c0 = (tid & 127) << 1, tg = tid >> 7;
  int t0 = half * 100;
  float acc0[25], acc1[25];
#pragma unroll
  for (int j = 0; j < 25; ++j) { acc0[j] = 0.f; acc1[j] = 0.f; }
  for (int h = 0; h < HH; ++h) {
    const float* ab = att + ((size_t)(b * HH + h) * TT + t0) * TT;
    const bf16* vb = vp + (size_t)(b * HH + h) * TT * CIN;
    for (int s0 = 0; s0 < t0 + 100; s0 += 32) {  // causal skip: att==0 beyond
      int sw = TT - s0; if (sw > 32) sw = 32;
      __syncthreads();
      for (int idx = tid; idx < 100 * 32; idx += 512) {
        int si = idx & 31, tl = idx >> 5;
        al[idx] = (si < sw) ? ab[(size_t)tl * TT + s0 + si] : 0.f;
      }
      for (int idx = tid; idx < 32 * 256; idx += 512) {
        int cc = idx & 255, si = idx >> 8;
        vl[si][cc] = (si < sw) ? __bfloat162float(vb[(size_t)(s0 + si) * CIN + cc]) : 0.f;
      }
      __syncthreads();
#pragma unroll 2
      for (int si4 = 0; si4 < 8; ++si4) {
        float2 v0 = *(const float2*)&vl[si4 * 4 + 0][c0];
        float2 v1 = *(const float2*)&vl[si4 * 4 + 1][c0];
        float2 v2 = *(const float2*)&vl[si4 * 4 + 2][c0];
        float2 v3 = *(const float2*)&vl[si4 * 4 + 3][c0];
#pragma unroll
        for (int j = 0; j < 25; ++j) {
          float4 a = *(const float4*)&al[(tg * 25 + j) * 32 + si4 * 4];
          acc0[j] += a.x * v0.x + a.y * v1.x + a.z * v2.x + a.w * v3.x;
          acc1[j] += a.x * v0.y + a.y * v1.y + a.z * v2.y + a.w * v3.y;
        }
      }
    }
  }
  float b0 = bp[c0], b1 = bp[c0 + 1];
#pragma unroll
  for (int j = 0; j < 25; ++j) {
    int t = t0 + tg * 25 + j;
    at[(size_t)b * CIN * TT + (size_t)c0 * TT + t] = acc0[j] + b0;
    at[(size_t)b * CIN * TT + (size_t)(c0 + 1) * TT + t] = acc1[j] + b1;
  }
}

// ---------------- K6: dilated causal conv (ReLU) then + residual (ReLU) ----------------
// Reference does TWO ReLUs:  out = relu( relu(conv + bc) + (Wd.x + bd) )
// so conv and residual accumulate SEPARATELY.
__global__ __launch_bounds__(256) void k_conv(const float* __restrict__ at,
    const float* __restrict__ x, const float* __restrict__ Wc, const float* __restrict__ bc,
    const float* __restrict__ Wd, const float* __restrict__ bd, float* __restrict__ out0) {
  __shared__ __align__(16) float aol[16][204];
  __shared__ __align__(16) float xl[16][200];
  __shared__ __align__(16) float wcl[16][3][64];
  __shared__ __align__(16) float wdl[16][64];
  int blk = blockIdx.x, b = blk >> 3, o0 = (blk & 7) << 6;
  int tid = threadIdx.x;
  int ol = (tid & 31) << 1, tg = tid >> 5;
  float c0a[25], c1a[25], r0a[25], r1a[25];
#pragma unroll
  for (int j = 0; j < 25; ++j) { c0a[j] = 0.f; c1a[j] = 0.f; r0a[j] = 0.f; r1a[j] = 0.f; }
  const float* atb = at + (size_t)b * CIN * TT;
  const float* xb = x + (size_t)b * CIN * TT;
  for (int i0 = 0; i0 < CIN; i0 += 16) {
    __syncthreads();
    for (int idx = tid; idx < 16 * 204; idx += 256) {
      int col = idx % 204, ii = idx / 204;
      aol[ii][col] = (col >= 4) ? atb[(size_t)(i0 + ii) * TT + col - 4] : 0.f;
    }
    for (int idx = tid; idx < 16 * 200; idx += 256) {
      int t = idx % 200, ii = idx / 200;
      xl[ii][t] = xb[(size_t)(i0 + ii) * TT + t];
    }
    for (int idx = tid; idx < 16 * 3 * 64; idx += 256) {
      int o = idx & 63, r = idx >> 6;
      int jj = r % 3, ii = r / 3;
      wcl[ii][jj][o] = Wc[(size_t)(o0 + o) * CIN * 3 + (size_t)(i0 + ii) * 3 + jj];
    }
    for (int idx = tid; idx < 16 * 64; idx += 256) {
      int o = idx & 63, ii = idx >> 6;
      wdl[ii][o] = Wd[(size_t)(o0 + o) * CIN + i0 + ii];
    }
    __syncthreads();
    for (int ii = 0; ii < 16; ++ii) {
      float w00 = wcl[ii][0][ol], w01 = wcl[ii][1][ol], w02 = wcl[ii][2][ol];
      float w10 = wcl[ii][0][ol + 1], w11 = wcl[ii][1][ol + 1], w12 = wcl[ii][2][ol + 1];
      float wd0 = wdl[ii][ol], wd1 = wdl[ii][ol + 1];
#pragma unroll
      for (int j = 0; j < 25; ++j) {
        int t = tg + (j << 3);
        float a0 = aol[ii][t], a1 = aol[ii][t + 2], a2 = aol[ii][t + 4];
        float xv = xl[ii][t];
        c0a[j] += w00 * a0 + w01 * a1 + w02 * a2;
        c1a[j] += w10 * a0 + w11 * a1 + w12 * a2;
        r0a[j] += wd0 * xv;
        r1a[j] += wd1 * xv;
      }
    }
  }
  float bc0 = bc[o0 + ol], bc1 = bc[o0 + ol + 1];
  float bd0 = bd[o0 + ol], bd1 = bd[o0 + ol + 1];
#pragma unroll
  for (int j = 0; j < 25; ++j) {
    int t = tg + (j << 3);
    float conv0 = fmaxf(c0a[j] + bc0, 0.f);
    float conv1 = fmaxf(c1a[j] + bc1, 0.f);
    out0[(size_t)b * COUT * TT + (size_t)(o0 + ol) * TT + t] = fmaxf(conv0 + r0a[j] + bd0, 0.f);
    out0[(size_t)b * COUT * TT + (size_t)(o0 + ol + 1) * TT + t] = fmaxf(conv1 + r1a[j] + bd1, 0.f);
  }
}

extern "C" void kernel_launch(void* const* d_in, const int* in_sizes, int n_in,
                              void* d_out, int out_size, void* d_ws, size_t ws_size,
                              hipStream_t stream) {
  const float* x  = (const float*)d_in[0];
  const float* Wq = (const float*)d_in[1];
  const float* bq = (const float*)d_in[2];
  const float* Wk = (const float*)d_in[3];
  const float* bk = (const float*)d_in[4];
  const float* Wv = (const float*)d_in[5];
  const float* bv = (const float*)d_in[6];
  const float* Wp = (const float*)d_in[7];
  const float* bp = (const float*)d_in[8];
  const float* Wc = (const float*)d_in[9];
  const float* bc = (const float*)d_in[10];
  const float* Wd = (const float*)d_in[11];
  const float* bd = (const float*)d_in[12];

  float* out0 = (float*)d_out;
  float* att  = out0 + (size_t)BB * COUT * TT;  // second output, (B,H,T,T)

  char* ws = (char*)d_ws;
  bf16*  qo  = (bf16*)(ws);                      // 26,214,400 B
  bf16*  ko  = (bf16*)(ws + 26214400);           // 26,214,400 B
  bf16*  vp  = (bf16*)(ws + 52428800);           // 104,857,600 B
  float* at  = (float*)(ws + 157286400);         // 26,214,400 B (B,C,T)
  float* Wvp = (float*)(ws + 183500800);         // 2,097,152 B
  float* bvp = (float*)(ws + 185597952);         // 8,192 B  -> total ~177 MB

  hipLaunchKernelGGL(k_wvp,  dim3(128),     dim3(256), 0, stream, Wv, Wp, bv, Wvp, bvp);
  hipLaunchKernelGGL(k_qk,   dim3(BB * HH), dim3(256), 0, stream, x, Wq, bq, Wk, bk, qo, ko);
  hipLaunchKernelGGL(k_vp,   dim3(BB * HH), dim3(256), 0, stream, x, Wvp, bvp, vp);
  hipLaunchKernelGGL(k_attn, dim3(BB * HH), dim3(512), 0, stream, qo, ko, att);
  hipLaunchKernelGGL(k_av,   dim3(BB * 2),  dim3(512), 0, stream, att, vp, bp, at);
  hipLaunchKernelGGL(k_conv, dim3(BB * 8),  dim3(256), 0, stream, at, x, Wc, bc, Wd, bd, out0);
}

// Round 4
// 1289.798 us; speedup vs baseline: 2.2624x; 2.2624x over previous
//
#include <hip/hip_runtime.h>
#include <hip/hip_bf16.h>
#include <math.h>

#define BB 128
#define CIN 256
#define COUT 512
#define TT 200
#define HH 8
#define KD 64
#define HK 512
#define HC 2048

typedef __hip_bfloat16 bf16;
typedef __attribute__((ext_vector_type(8))) short s16x8;
typedef __attribute__((ext_vector_type(4))) short s16x4;
typedef __attribute__((ext_vector_type(4))) float f32x4;

#define MFMA(a, b, c) __builtin_amdgcn_mfma_f32_16x16x32_bf16(a, b, c, 0, 0, 0)

__device__ __forceinline__ short bfs(float f) {
  bf16 h = __float2bfloat16(f);
  return *reinterpret_cast<short*>(&h);
}
__device__ __forceinline__ s16x8 ld8(const bf16* p) {
  return *reinterpret_cast<const s16x8*>(p);
}

// ---------------- K_xb: xb[b][t][c] bf16 <- transpose x (B,C,T) f32; rows 200..207 zero --------
__global__ __launch_bounds__(256) void k_xb(const float* __restrict__ x, bf16* __restrict__ xb) {
  __shared__ float lx[CIN][33];
  int blk = blockIdx.x, b = blk / 7, tt = blk % 7, t0 = tt * 32;
  int tid = threadIdx.x;
  const float* xbp = x + (size_t)b * CIN * TT;
  bf16* xo = xb + (size_t)b * 208 * CIN;
  for (int idx = tid; idx < CIN * 32; idx += 256) {
    int c = idx >> 5, tl = idx & 31, t = t0 + tl;
    lx[c][tl] = (t < TT) ? xbp[(size_t)c * TT + t] : 0.f;
  }
  __syncthreads();
  for (int idx = tid; idx < 32 * 64; idx += 256) {
    int tl = idx >> 6, cs = idx & 63, t = t0 + tl;
    if (t < TT) {
      s16x4 p;
      p[0] = bfs(lx[cs * 4 + 0][tl]); p[1] = bfs(lx[cs * 4 + 1][tl]);
      p[2] = bfs(lx[cs * 4 + 2][tl]); p[3] = bfs(lx[cs * 4 + 3][tl]);
      *reinterpret_cast<s16x4*>(&xo[(size_t)t * CIN + cs * 4]) = p;
    }
  }
  if (tt == 6) {
    s16x4 z = {0, 0, 0, 0};
    for (int idx = tid; idx < 8 * 64; idx += 256) {
      int r = 200 + (idx >> 6), cs = idx & 63;
      *reinterpret_cast<s16x4*>(&xo[(size_t)r * CIN + cs * 4]) = z;
    }
  }
}

// ---------------- K_wc: pack conv/residual weights bf16: Wcb[j][o][i], Wdb[o][i] ----------------
__global__ __launch_bounds__(256) void k_wc(const float* __restrict__ Wc,
    const float* __restrict__ Wd, bf16* __restrict__ Wcb, bf16* __restrict__ Wdb) {
  int o = blockIdx.x, i = threadIdx.x;
  size_t oi = (size_t)o * CIN + i;
#pragma unroll
  for (int j = 0; j < 3; ++j)
    Wcb[(size_t)j * COUT * CIN + oi] = __float2bfloat16(Wc[oi * 3 + j]);
  Wdb[oi] = __float2bfloat16(Wd[oi]);
}

// ---------------- K1: fold Wv @ Wp_h -> WvpT[h][c][ci] bf16, bvp[h][c] f32 ----------------
__global__ __launch_bounds__(256) void k_wvp(const float* __restrict__ Wv,
    const float* __restrict__ Wp, const float* __restrict__ bv,
    bf16* __restrict__ WvpT, float* __restrict__ bvp) {
  __shared__ __align__(16) float wpl[32][256];
  __shared__ __align__(16) float wvl[17][32];
  int h = blockIdx.x >> 4, ci0 = (blockIdx.x & 15) << 4;
  int c = threadIdx.x;
  float acc[17];
#pragma unroll
  for (int i = 0; i < 17; ++i) acc[i] = 0.f;
  for (int p0 = 0; p0 < CIN; p0 += 32) {
    __syncthreads();
    for (int idx = c; idx < 17 * 32; idx += 256) {
      int pp = idx & 31, cil = idx >> 5;
      wvl[cil][pp] = (cil < 16) ? Wv[(size_t)(ci0 + cil) * HC + h * CIN + p0 + pp]
                                : bv[h * CIN + p0 + pp];
    }
    for (int idx = c; idx < 32 * 256; idx += 256) {
      int cc = idx & 255, pp = idx >> 8;
      wpl[pp][cc] = Wp[(size_t)(h * CIN + p0 + pp) * CIN + cc];
    }
    __syncthreads();
#pragma unroll 4
    for (int pp = 0; pp < 32; ++pp) {
      float w = wpl[pp][c];
#pragma unroll
      for (int i = 0; i < 17; ++i) acc[i] += wvl[i][pp] * w;
    }
  }
  for (int i = 0; i < 16; ++i)
    WvpT[((size_t)h * CIN + c) * CIN + ci0 + i] = __float2bfloat16(acc[i]);
  if (ci0 == 0) bvp[h * CIN + c] = acc[16];
}

// ---------------- K2: q,k projection (f32 VALU) -> bf16 [bh][t][64] ----------------
__global__ __launch_bounds__(256) void k_qk(const float* __restrict__ x,
    const float* __restrict__ Wq, const float* __restrict__ bq,
    const float* __restrict__ Wk, const float* __restrict__ bk,
    bf16* __restrict__ qo, bf16* __restrict__ ko) {
  __shared__ __align__(16) float xl[32][32];
  __shared__ __align__(16) float wql[32][64];
  __shared__ __align__(16) float wkl[32][64];
  int bh = blockIdx.x, b = bh >> 3, h = bh & 7;
  int tid = threadIdx.x, kk = tid & 63, tg = tid >> 6;
  const float* xb = x + (size_t)b * CIN * TT;
  float biasq = bq[h * KD + kk], biask = bk[h * KD + kk];
  for (int t0 = 0; t0 < TT; t0 += 32) {
    float accq[8], acck[8];
#pragma unroll
    for (int j = 0; j < 8; ++j) { accq[j] = 0.f; acck[j] = 0.f; }
    for (int c0 = 0; c0 < CIN; c0 += 32) {
      __syncthreads();
      for (int idx = tid; idx < 32 * 32; idx += 256) {
        int t = idx & 31, cii = idx >> 5;
        xl[cii][t] = (t0 + t < TT) ? xb[(size_t)(c0 + cii) * TT + t0 + t] : 0.f;
      }
      for (int idx = tid; idx < 32 * 64; idx += 256) {
        int k2 = idx & 63, cii = idx >> 6;
        wql[cii][k2] = Wq[(size_t)(c0 + cii) * HK + h * KD + k2];
        wkl[cii][k2] = Wk[(size_t)(c0 + cii) * HK + h * KD + k2];
      }
      __syncthreads();
#pragma unroll 4
      for (int cii = 0; cii < 32; ++cii) {
        float wq = wql[cii][kk], wk = wkl[cii][kk];
        const float4* xr = (const float4*)xl[cii];
        float4 x0 = xr[tg * 2], x1 = xr[tg * 2 + 1];
        accq[0] += x0.x * wq; accq[1] += x0.y * wq; accq[2] += x0.z * wq; accq[3] += x0.w * wq;
        accq[4] += x1.x * wq; accq[5] += x1.y * wq; accq[6] += x1.z * wq; accq[7] += x1.w * wq;
        acck[0] += x0.x * wk; acck[1] += x0.y * wk; acck[2] += x0.z * wk; acck[3] += x0.w * wk;
        acck[4] += x1.x * wk; acck[5] += x1.y * wk; acck[6] += x1.z * wk; acck[7] += x1.w * wk;
      }
    }
    size_t base = (size_t)bh * TT * KD;
#pragma unroll
    for (int j = 0; j < 8; ++j) {
      int t = t0 + tg * 8 + j;
      if (t < TT) {
        qo[base + (size_t)t * KD + kk] = __float2bfloat16(accq[j] + biasq);
        ko[base + (size_t)t * KD + kk] = __float2bfloat16(acck[j] + biask);
      }
    }
  }
}

// ---------------- K4: per-(b,h) scores + causal softmax -> att (f32, d_out) ----------------
__global__ __launch_bounds__(512) void k_attn(const bf16* __restrict__ qo,
    const bf16* __restrict__ ko, float* __restrict__ att) {
  __shared__ __align__(16) float ql[TT][64];
  __shared__ __align__(16) float kl[TT][65];
  int bh = blockIdx.x, tid = threadIdx.x;
  const bf16* qb = qo + (size_t)bh * TT * KD;
  const bf16* kb = ko + (size_t)bh * TT * KD;
  for (int idx = tid; idx < TT * KD; idx += 512) {
    int k2 = idx & 63, t = idx >> 6;
    ql[t][k2] = __bfloat162float(qb[idx]);
    kl[t][k2] = __bfloat162float(kb[idx]);
  }
  __syncthreads();
  int lane = tid & 63, w = tid >> 6;
  float* ab = att + (size_t)bh * TT * TT;
  for (int t = w; t < TT; t += 8) {
    float val[4];
    int simax = t >> 6;
#pragma unroll
    for (int si = 0; si < 4; ++si) {
      int s = lane + (si << 6);
      if (si <= simax && s <= t) {
        float acc = 0.f;
#pragma unroll 8
        for (int ci = 0; ci < KD; ++ci) acc += ql[t][ci] * kl[s][ci];
        val[si] = acc * 0.125f;
      } else val[si] = -INFINITY;
    }
    float m = fmaxf(fmaxf(val[0], val[1]), fmaxf(val[2], val[3]));
#pragma unroll
    for (int off = 32; off; off >>= 1) m = fmaxf(m, __shfl_xor(m, off));
    float e[4], sum = 0.f;
#pragma unroll
    for (int si = 0; si < 4; ++si) {
      e[si] = (val[si] > -INFINITY) ? __expf(val[si] - m) : 0.f;
      sum += e[si];
    }
#pragma unroll
    for (int off = 32; off; off >>= 1) sum += __shfl_xor(sum, off);
    float inv = 1.f / sum;
#pragma unroll
    for (int si = 0; si < 4; ++si) {
      int s = lane + (si << 6);
      if (s < TT) ab[(size_t)t * TT + s] = e[si] * inv;
    }
  }
}

// ---------------- K3 (MFMA): vpT[bh][c][s] = (xb @ WvpT_h^T + bvp), bf16 ----------------
__global__ __launch_bounds__(256) void k_vp(const bf16* __restrict__ xb,
    const bf16* __restrict__ WvpT, const float* __restrict__ bvp, bf16* __restrict__ vpT) {
  int blk = blockIdx.x;
  int b = blk >> 5, h = (blk >> 2) & 7, q = blk & 3;
  int tid = threadIdx.x, w = tid >> 6, l = tid & 63;
  int lrow = l & 15, g = l >> 4;
  int cw = q * 64 + w * 16 + lrow;
  const bf16* xbb = xb + (size_t)b * 208 * CIN;
  const bf16* wvt = WvpT + ((size_t)h * CIN + cw) * CIN;
  f32x4 acc[13];
#pragma unroll
  for (int mt = 0; mt < 13; ++mt) acc[mt] = (f32x4){0.f, 0.f, 0.f, 0.f};
  for (int kc = 0; kc < 8; ++kc) {
    int ko = kc * 32 + g * 8;
    s16x8 bfr = ld8(&wvt[ko]);
#pragma unroll
    for (int mt = 0; mt < 13; ++mt) {
      s16x8 afr = ld8(&xbb[(size_t)(mt * 16 + lrow) * CIN + ko]);
      acc[mt] = MFMA(afr, bfr, acc[mt]);
    }
  }
  float bias = bvp[h * CIN + cw];
  bf16* vout = vpT + ((size_t)(b * 8 + h) * CIN + cw) * TT;
#pragma unroll
  for (int mt = 0; mt < 13; ++mt) {
    int s = mt * 16 + g * 4;
    if (s < TT) {
      s16x4 p;
      p[0] = bfs(acc[mt][0] + bias); p[1] = bfs(acc[mt][1] + bias);
      p[2] = bfs(acc[mt][2] + bias); p[3] = bfs(acc[mt][3] + bias);
      *reinterpret_cast<s16x4*>(&vout[s]) = p;
    }
  }
}

// ---------------- K5 (MFMA): atTp[b][t+4][c] = sum_h att_h @ vp_h + bp, bf16, causal skip ------
// K-tail guard: s>=TT lanes zeroed on BOTH A (att tile) and B (vpT) sides.
__global__ __launch_bounds__(256) void k_av(const float* __restrict__ att,
    const bf16* __restrict__ vpT, const float* __restrict__ bp, bf16* __restrict__ atTp) {
  __shared__ short lsm[208 * 40];  // 208 rows x 32 bf16, 80B padded rows
  int blk = blockIdx.x, b = blk >> 2, q = blk & 3;
  int n0 = q * 64;
  int tid = threadIdx.x, w = tid >> 6, l = tid & 63;
  int lrow = l & 15, g = l >> 4;
  int cw = n0 + w * 16 + lrow;
  bf16* atb = atTp + (size_t)b * 216 * CIN;
  bf16 zb = __float2bfloat16(0.f);
  for (int idx = tid; idx < 12 * 64; idx += 256) {
    int rr = idx >> 6, cc = idx & 63;
    int row = (rr < 4) ? rr : rr + 200;
    atb[(size_t)row * CIN + n0 + cc] = zb;
  }
  f32x4 acc[13];
#pragma unroll
  for (int mt = 0; mt < 13; ++mt) acc[mt] = (f32x4){0.f, 0.f, 0.f, 0.f};
  for (int h = 0; h < HH; ++h) {
    const float* abh = att + (size_t)(b * 8 + h) * TT * TT;
    const bf16* vbh = vpT + (size_t)(b * 8 + h) * CIN * TT;
    for (int s0 = 0; s0 < TT; s0 += 32) {
      __syncthreads();
      for (int idx = tid; idx < 208 * 8; idx += 256) {
        int row = idx >> 3, sl = idx & 7;
        float4 v = {0.f, 0.f, 0.f, 0.f};
        if (row < TT && s0 + sl * 4 < TT)  // tail guard: s>=TT -> 0
          v = *(const float4*)&abh[(size_t)row * TT + s0 + sl * 4];
        s16x4 p;
        p[0] = bfs(v.x); p[1] = bfs(v.y); p[2] = bfs(v.z); p[3] = bfs(v.w);
        *reinterpret_cast<s16x4*>(&lsm[row * 40 + sl * 4]) = p;
      }
      __syncthreads();
      s16x8 bfr = (s0 + g * 8 < TT) ? ld8(&vbh[(size_t)cw * TT + s0 + g * 8])
                                    : (s16x8){0, 0, 0, 0, 0, 0, 0, 0};
#pragma unroll
      for (int mt = 0; mt < 13; ++mt) {
        if ((mt << 4) + 16 > s0) {  // causal: tile has rows t >= s0
          s16x8 afr = *reinterpret_cast<const s16x8*>(&lsm[(mt * 16 + lrow) * 40 + g * 8]);
          acc[mt] = MFMA(afr, bfr, acc[mt]);
        }
      }
    }
  }
  float bpv = bp[cw];
#pragma unroll
  for (int mt = 0; mt < 13; ++mt) {
#pragma unroll
    for (int r = 0; r < 4; ++r) {
      int t = mt * 16 + g * 4 + r;
      if (t < TT) atb[(size_t)(t + 4) * CIN + cw] = __float2bfloat16(acc[mt][r] + bpv);
    }
  }
}

// ---------------- K6 (MFMA): dilated conv (3 taps) + residual, two ReLUs ----------------
__global__ __launch_bounds__(256) void k_conv(const bf16* __restrict__ atTp,
    const bf16* __restrict__ xb, const bf16* __restrict__ Wcb, const bf16* __restrict__ Wdb,
    const float* __restrict__ bc, const float* __restrict__ bd, float* __restrict__ out0) {
  int blk = blockIdx.x, b = blk >> 3, og = blk & 7;
  int tid = threadIdx.x, w = tid >> 6, l = tid & 63;
  int lrow = l & 15, g = l >> 4;
  int o0 = og * 64 + w * 16;
  const bf16* wc0 = Wcb + (size_t)(o0 + lrow) * CIN;
  const bf16* wc1 = wc0 + (size_t)COUT * CIN;
  const bf16* wc2 = wc1 + (size_t)COUT * CIN;
  const bf16* wdp = Wdb + (size_t)(o0 + lrow) * CIN;
  const bf16* atb = atTp + (size_t)b * 216 * CIN;
  const bf16* xbb = xb + (size_t)b * 208 * CIN;
  f32x4 accc[13], accr[13];
#pragma unroll
  for (int nt = 0; nt < 13; ++nt) {
    accc[nt] = (f32x4){0.f, 0.f, 0.f, 0.f};
    accr[nt] = (f32x4){0.f, 0.f, 0.f, 0.f};
  }
  for (int kc = 0; kc < 8; ++kc) {
    int ko = kc * 32 + g * 8;
    s16x8 a0 = ld8(&wc0[ko]);
    s16x8 a1 = ld8(&wc1[ko]);
    s16x8 a2 = ld8(&wc2[ko]);
    s16x8 ad = ld8(&wdp[ko]);
#pragma unroll
    for (int nt = 0; nt < 13; ++nt) {
      int tb = nt * 16 + lrow;
      s16x8 b0 = ld8(&atb[(size_t)(tb + 0) * CIN + ko]);
      s16x8 b1 = ld8(&atb[(size_t)(tb + 2) * CIN + ko]);
      s16x8 b2 = ld8(&atb[(size_t)(tb + 4) * CIN + ko]);
      s16x8 bx = ld8(&xbb[(size_t)tb * CIN + ko]);
      accc[nt] = MFMA(a0, b0, accc[nt]);
      accc[nt] = MFMA(a1, b1, accc[nt]);
      accc[nt] = MFMA(a2, b2, accc[nt]);
      accr[nt] = MFMA(ad, bx, accr[nt]);
    }
  }
  f32x4 bcv = *reinterpret_cast<const f32x4*>(&bc[o0 + g * 4]);
  f32x4 bdv = *reinterpret_cast<const f32x4*>(&bd[o0 + g * 4]);
#pragma unroll
  for (int nt = 0; nt < 13; ++nt) {
    int t = nt * 16 + lrow;
    if (t < TT) {
#pragma unroll
      for (int r = 0; r < 4; ++r) {
        int o = o0 + g * 4 + r;
        float conv = fmaxf(accc[nt][r] + bcv[r], 0.f);
        out0[((size_t)b * COUT + o) * TT + t] = fmaxf(conv + accr[nt][r] + bdv[r], 0.f);
      }
    }
  }
}

extern "C" void kernel_launch(void* const* d_in, const int* in_sizes, int n_in,
                              void* d_out, int out_size, void* d_ws, size_t ws_size,
                              hipStream_t stream) {
  const float* x  = (const float*)d_in[0];
  const float* Wq = (const float*)d_in[1];
  const float* bq = (const float*)d_in[2];
  const float* Wk = (const float*)d_in[3];
  const float* bk = (const float*)d_in[4];
  const float* Wv = (const float*)d_in[5];
  const float* bv = (const float*)d_in[6];
  const float* Wp = (const float*)d_in[7];
  const float* bp = (const float*)d_in[8];
  const float* Wc = (const float*)d_in[9];
  const float* bc = (const float*)d_in[10];
  const float* Wd = (const float*)d_in[11];
  const float* bd = (const float*)d_in[12];

  float* out0 = (float*)d_out;
  float* att  = out0 + (size_t)BB * COUT * TT;  // second output, (B,H,T,T)

  char* ws = (char*)d_ws;
  // qo (dead after k_attn) shares space with atTp (written by k_av)
  bf16*  qo   = (bf16*)(ws);                     // 26,214,400 B
  bf16*  atTp = (bf16*)(ws);                     // 14,155,776 B  (B x 216 x 256)
  bf16*  ko   = (bf16*)(ws + 26214400);          // 26,214,400 B
  bf16*  vpT  = (bf16*)(ws + 52428800);          // 104,857,600 B (BH x 256 x 200)
  bf16*  xb   = (bf16*)(ws + 157286400);         // 13,631,488 B  (B x 208 x 256)
  bf16*  WvpT = (bf16*)(ws + 170917888);         // 1,048,576 B
  float* bvp  = (float*)(ws + 171966464);        // 8,192 B
  bf16*  Wcb  = (bf16*)(ws + 171974656);         // 786,432 B
  bf16*  Wdb  = (bf16*)(ws + 172761088);         // 262,144 B -> end 173,023,232

  hipLaunchKernelGGL(k_wvp,  dim3(128),      dim3(256), 0, stream, Wv, Wp, bv, WvpT, bvp);
  hipLaunchKernelGGL(k_wc,   dim3(COUT),     dim3(256), 0, stream, Wc, Wd, Wcb, Wdb);
  hipLaunchKernelGGL(k_xb,   dim3(BB * 7),   dim3(256), 0, stream, x, xb);
  hipLaunchKernelGGL(k_qk,   dim3(BB * HH),  dim3(256), 0, stream, x, Wq, bq, Wk, bk, qo, ko);
  hipLaunchKernelGGL(k_attn, dim3(BB * HH),  dim3(512), 0, stream, qo, ko, att);
  hipLaunchKernelGGL(k_vp,   dim3(BB * 32),  dim3(256), 0, stream, xb, WvpT, bvp, vpT);
  hipLaunchKernelGGL(k_av,   dim3(BB * 4),   dim3(256), 0, stream, att, vpT, bp, atTp);
  hipLaunchKernelGGL(k_conv, dim3(BB * 8),   dim3(256), 0, stream, atTp, xb, Wcb, Wdb, bc, bd, out0);
}

// Round 5
// 901.075 us; speedup vs baseline: 3.2384x; 1.4314x over previous
//
#include <hip/hip_runtime.h>
#include <hip/hip_bf16.h>
#include <math.h>

#define BB 128
#define CIN 256
#define COUT 512
#define TT 200
#define HH 8
#define KD 64
#define HK 512
#define HC 2048

typedef __hip_bfloat16 bf16;
typedef __attribute__((ext_vector_type(8))) short s16x8;
typedef __attribute__((ext_vector_type(4))) short s16x4;
typedef __attribute__((ext_vector_type(4))) float f32x4;

#define MFMA(a, b, c) __builtin_amdgcn_mfma_f32_16x16x32_bf16(a, b, c, 0, 0, 0)

__device__ __forceinline__ short bfs(float f) {
  bf16 h = __float2bfloat16(f);
  return *reinterpret_cast<short*>(&h);
}
__device__ __forceinline__ s16x8 ld8(const bf16* p) {
  return *reinterpret_cast<const s16x8*>(p);
}

// ---------------- K_xb: xb[b][t][c] bf16 <- transpose x (B,C,T) f32; rows 200..207 zero --------
__global__ __launch_bounds__(256) void k_xb(const float* __restrict__ x, bf16* __restrict__ xb) {
  __shared__ float lx[CIN][33];
  int blk = blockIdx.x, b = blk / 7, tt = blk % 7, t0 = tt * 32;
  int tid = threadIdx.x;
  const float* xbp = x + (size_t)b * CIN * TT;
  bf16* xo = xb + (size_t)b * 208 * CIN;
  for (int idx = tid; idx < CIN * 32; idx += 256) {
    int c = idx >> 5, tl = idx & 31, t = t0 + tl;
    lx[c][tl] = (t < TT) ? xbp[(size_t)c * TT + t] : 0.f;
  }
  __syncthreads();
  for (int idx = tid; idx < 32 * 64; idx += 256) {
    int tl = idx >> 6, cs = idx & 63, t = t0 + tl;
    if (t < TT) {
      s16x4 p;
      p[0] = bfs(lx[cs * 4 + 0][tl]); p[1] = bfs(lx[cs * 4 + 1][tl]);
      p[2] = bfs(lx[cs * 4 + 2][tl]); p[3] = bfs(lx[cs * 4 + 3][tl]);
      *reinterpret_cast<s16x4*>(&xo[(size_t)t * CIN + cs * 4]) = p;
    }
  }
  if (tt == 6) {
    s16x4 z = {0, 0, 0, 0};
    for (int idx = tid; idx < 8 * 64; idx += 256) {
      int r = 200 + (idx >> 6), cs = idx & 63;
      *reinterpret_cast<s16x4*>(&xo[(size_t)r * CIN + cs * 4]) = z;
    }
  }
}

// ---------------- K_wc: pack conv/residual weights bf16: Wcb[j][o][i], Wdb[o][i] ----------------
__global__ __launch_bounds__(256) void k_wc(const float* __restrict__ Wc,
    const float* __restrict__ Wd, bf16* __restrict__ Wcb, bf16* __restrict__ Wdb) {
  int o = blockIdx.x, i = threadIdx.x;
  size_t oi = (size_t)o * CIN + i;
#pragma unroll
  for (int j = 0; j < 3; ++j)
    Wcb[(size_t)j * COUT * CIN + oi] = __float2bfloat16(Wc[oi * 3 + j]);
  Wdb[oi] = __float2bfloat16(Wd[oi]);
}

// ---------------- K_wqk: pack WqT[n][ci], WkT[n][ci] bf16 (transpose of (CIN,HK)) -------------
__global__ __launch_bounds__(256) void k_wqk(const float* __restrict__ Wq,
    const float* __restrict__ Wk, bf16* __restrict__ WqT, bf16* __restrict__ WkT) {
  int n = blockIdx.x, ci = threadIdx.x;
  WqT[(size_t)n * CIN + ci] = __float2bfloat16(Wq[(size_t)ci * HK + n]);
  WkT[(size_t)n * CIN + ci] = __float2bfloat16(Wk[(size_t)ci * HK + n]);
}

// ---------------- K1: fold Wv @ Wp_h -> WvpT[h][c][ci] bf16, bvp[h][c] f32 ----------------
__global__ __launch_bounds__(256) void k_wvp(const float* __restrict__ Wv,
    const float* __restrict__ Wp, const float* __restrict__ bv,
    bf16* __restrict__ WvpT, float* __restrict__ bvp) {
  __shared__ __align__(16) float wpl[32][256];
  __shared__ __align__(16) float wvl[17][32];
  int h = blockIdx.x >> 4, ci0 = (blockIdx.x & 15) << 4;
  int c = threadIdx.x;
  float acc[17];
#pragma unroll
  for (int i = 0; i < 17; ++i) acc[i] = 0.f;
  for (int p0 = 0; p0 < CIN; p0 += 32) {
    __syncthreads();
    for (int idx = c; idx < 17 * 32; idx += 256) {
      int pp = idx & 31, cil = idx >> 5;
      wvl[cil][pp] = (cil < 16) ? Wv[(size_t)(ci0 + cil) * HC + h * CIN + p0 + pp]
                                : bv[h * CIN + p0 + pp];
    }
    for (int idx = c; idx < 32 * 256; idx += 256) {
      int cc = idx & 255, pp = idx >> 8;
      wpl[pp][cc] = Wp[(size_t)(h * CIN + p0 + pp) * CIN + cc];
    }
    __syncthreads();
#pragma unroll 4
    for (int pp = 0; pp < 32; ++pp) {
      float w = wpl[pp][c];
#pragma unroll
      for (int i = 0; i < 17; ++i) acc[i] += wvl[i][pp] * w;
    }
  }
  for (int i = 0; i < 16; ++i)
    WvpT[((size_t)h * CIN + c) * CIN + ci0 + i] = __float2bfloat16(acc[i]);
  if (ci0 == 0) bvp[h * CIN + c] = acc[16];
}

// ---------------- K2 (MFMA): q,k = xb @ {WqT,WkT}^T + bias -> bf16 [b][t][HK] ----------------
__global__ __launch_bounds__(256) void k_qk(const bf16* __restrict__ xb,
    const bf16* __restrict__ WqT, const bf16* __restrict__ WkT,
    const float* __restrict__ bq, const float* __restrict__ bk,
    bf16* __restrict__ qo, bf16* __restrict__ kvo) {
  int blk = blockIdx.x, b = blk >> 3, quad = blk & 7;
  int tid = threadIdx.x, w = tid >> 6, l = tid & 63;
  int lrow = l & 15, g = l >> 4;
  int cw = quad * 64 + w * 16 + lrow;
  const bf16* xbb = xb + (size_t)b * 208 * CIN;
  const bf16* wqt = WqT + (size_t)cw * CIN;
  const bf16* wkt = WkT + (size_t)cw * CIN;
  f32x4 aq[13], ak[13];
#pragma unroll
  for (int mt = 0; mt < 13; ++mt) {
    aq[mt] = (f32x4){0.f, 0.f, 0.f, 0.f};
    ak[mt] = (f32x4){0.f, 0.f, 0.f, 0.f};
  }
  for (int kc = 0; kc < 8; ++kc) {
    int kof = kc * 32 + g * 8;
    s16x8 bqf = ld8(&wqt[kof]);
    s16x8 bkf = ld8(&wkt[kof]);
#pragma unroll
    for (int mt = 0; mt < 13; ++mt) {
      s16x8 afr = ld8(&xbb[(size_t)(mt * 16 + lrow) * CIN + kof]);
      aq[mt] = MFMA(afr, bqf, aq[mt]);
      ak[mt] = MFMA(afr, bkf, ak[mt]);
    }
  }
  float bqv = bq[cw], bkv = bk[cw];
#pragma unroll
  for (int mt = 0; mt < 13; ++mt) {
#pragma unroll
    for (int r = 0; r < 4; ++r) {
      int t = mt * 16 + g * 4 + r;
      if (t < TT) {
        qo[((size_t)b * TT + t) * HK + cw] = __float2bfloat16(aq[mt][r] + bqv);
        kvo[((size_t)b * TT + t) * HK + cw] = __float2bfloat16(ak[mt][r] + bkv);
      }
    }
  }
}

// ---------------- K4 (MFMA): per-(b,h) causal scores + softmax -> att (f32, d_out) ------------
// No LDS: q/k slices (25.6 KB each) live in L1/L2. 4 waves; wave w owns m-tiles w, w+4, w+8, w+12.
__global__ __launch_bounds__(256) void k_attn(const bf16* __restrict__ qo,
    const bf16* __restrict__ kvo, float* __restrict__ att) {
  int bh = blockIdx.x, b = bh >> 3, h = bh & 7;
  int tid = threadIdx.x, w = tid >> 6, l = tid & 63;
  int lrow = l & 15, g = l >> 4;
  const bf16* qb = qo + (size_t)b * TT * HK + h * KD;
  const bf16* kb = kvo + (size_t)b * TT * HK + h * KD;
  float* ab = att + (size_t)bh * TT * TT;
  for (int mt = w; mt < 13; mt += 4) {
    int ra = mt * 16 + lrow; if (ra > TT - 1) ra = TT - 1;
    s16x8 a0 = ld8(&qb[(size_t)ra * HK + g * 8]);
    s16x8 a1 = ld8(&qb[(size_t)ra * HK + 32 + g * 8]);
    f32x4 sacc[13];
#pragma unroll
    for (int st = 0; st < 13; ++st) sacc[st] = (f32x4){0.f, 0.f, 0.f, 0.f};
#pragma unroll
    for (int st = 0; st < 13; ++st) {
      if (st <= mt) {
        int rb = st * 16 + lrow; if (rb > TT - 1) rb = TT - 1;
        s16x8 b0 = ld8(&kb[(size_t)rb * HK + g * 8]);
        s16x8 b1 = ld8(&kb[(size_t)rb * HK + 32 + g * 8]);
        sacc[st] = MFMA(a0, b0, sacc[st]);
        sacc[st] = MFMA(a1, b1, sacc[st]);
      }
    }
#pragma unroll
    for (int r = 0; r < 4; ++r) {
      int m = mt * 16 + g * 4 + r;
      if (m >= TT) continue;
      float vals[13];
      float mx = -INFINITY;
#pragma unroll
      for (int st = 0; st < 13; ++st) {
        int col = st * 16 + lrow;
        float v = sacc[st][r] * 0.125f;
        vals[st] = (st <= mt && col <= m) ? v : -INFINITY;
        mx = fmaxf(mx, vals[st]);
      }
#pragma unroll
      for (int off = 1; off < 16; off <<= 1) mx = fmaxf(mx, __shfl_xor(mx, off));
      float e[13], sum = 0.f;
#pragma unroll
      for (int st = 0; st < 13; ++st) {
        e[st] = (vals[st] > -INFINITY) ? __expf(vals[st] - mx) : 0.f;
        sum += e[st];
      }
#pragma unroll
      for (int off = 1; off < 16; off <<= 1) sum += __shfl_xor(sum, off);
      float inv = 1.f / sum;
#pragma unroll
      for (int st = 0; st < 13; ++st) {
        int col = st * 16 + lrow;
        if (col < TT) ab[(size_t)m * TT + col] = e[st] * inv;
      }
    }
  }
}

// ---------------- K3 (MFMA): vpT[bh][c][s] = (xb @ WvpT_h^T + bvp), bf16 ----------------
__global__ __launch_bounds__(256) void k_vp(const bf16* __restrict__ xb,
    const bf16* __restrict__ WvpT, const float* __restrict__ bvp, bf16* __restrict__ vpT) {
  int blk = blockIdx.x;
  int b = blk >> 5, h = (blk >> 2) & 7, q = blk & 3;
  int tid = threadIdx.x, w = tid >> 6, l = tid & 63;
  int lrow = l & 15, g = l >> 4;
  int cw = q * 64 + w * 16 + lrow;
  const bf16* xbb = xb + (size_t)b * 208 * CIN;
  const bf16* wvt = WvpT + ((size_t)h * CIN + cw) * CIN;
  f32x4 acc[13];
#pragma unroll
  for (int mt = 0; mt < 13; ++mt) acc[mt] = (f32x4){0.f, 0.f, 0.f, 0.f};
  for (int kc = 0; kc < 8; ++kc) {
    int kof = kc * 32 + g * 8;
    s16x8 bfr = ld8(&wvt[kof]);
#pragma unroll
    for (int mt = 0; mt < 13; ++mt) {
      s16x8 afr = ld8(&xbb[(size_t)(mt * 16 + lrow) * CIN + kof]);
      acc[mt] = MFMA(afr, bfr, acc[mt]);
    }
  }
  float bias = bvp[h * CIN + cw];
  bf16* vout = vpT + ((size_t)(b * 8 + h) * CIN + cw) * TT;
#pragma unroll
  for (int mt = 0; mt < 13; ++mt) {
    int s = mt * 16 + g * 4;
    if (s < TT) {
      s16x4 p;
      p[0] = bfs(acc[mt][0] + bias); p[1] = bfs(acc[mt][1] + bias);
      p[2] = bfs(acc[mt][2] + bias); p[3] = bfs(acc[mt][3] + bias);
      *reinterpret_cast<s16x4*>(&vout[s]) = p;
    }
  }
}

// ---------------- K5 (MFMA): atTp[b][t+4][c] = sum_h att_h @ vp_h + bp, bf16, causal skip ------
__global__ __launch_bounds__(256) void k_av(const float* __restrict__ att,
    const bf16* __restrict__ vpT, const float* __restrict__ bp, bf16* __restrict__ atTp) {
  __shared__ short lsm[208 * 40];  // 208 rows x 32 bf16, 80B padded rows
  int blk = blockIdx.x, b = blk >> 2, q = blk & 3;
  int n0 = q * 64;
  int tid = threadIdx.x, w = tid >> 6, l = tid & 63;
  int lrow = l & 15, g = l >> 4;
  int cw = n0 + w * 16 + lrow;
  bf16* atb = atTp + (size_t)b * 216 * CIN;
  bf16 zb = __float2bfloat16(0.f);
  for (int idx = tid; idx < 12 * 64; idx += 256) {
    int rr = idx >> 6, cc = idx & 63;
    int row = (rr < 4) ? rr : rr + 200;
    atb[(size_t)row * CIN + n0 + cc] = zb;
  }
  f32x4 acc[13];
#pragma unroll
  for (int mt = 0; mt < 13; ++mt) acc[mt] = (f32x4){0.f, 0.f, 0.f, 0.f};
  for (int h = 0; h < HH; ++h) {
    const float* abh = att + (size_t)(b * 8 + h) * TT * TT;
    const bf16* vbh = vpT + (size_t)(b * 8 + h) * CIN * TT;
    for (int s0 = 0; s0 < TT; s0 += 32) {
      __syncthreads();
      for (int idx = tid; idx < 208 * 8; idx += 256) {
        int row = idx >> 3, sl = idx & 7;
        float4 v = {0.f, 0.f, 0.f, 0.f};
        if (row < TT && s0 + sl * 4 < TT)
          v = *(const float4*)&abh[(size_t)row * TT + s0 + sl * 4];
        s16x4 p;
        p[0] = bfs(v.x); p[1] = bfs(v.y); p[2] = bfs(v.z); p[3] = bfs(v.w);
        *reinterpret_cast<s16x4*>(&lsm[row * 40 + sl * 4]) = p;
      }
      __syncthreads();
      s16x8 bfr = (s0 + g * 8 < TT) ? ld8(&vbh[(size_t)cw * TT + s0 + g * 8])
                                    : (s16x8){0, 0, 0, 0, 0, 0, 0, 0};
#pragma unroll
      for (int mt = 0; mt < 13; ++mt) {
        if ((mt << 4) + 16 > s0) {
          s16x8 afr = *reinterpret_cast<const s16x8*>(&lsm[(mt * 16 + lrow) * 40 + g * 8]);
          acc[mt] = MFMA(afr, bfr, acc[mt]);
        }
      }
    }
  }
  float bpv = bp[cw];
#pragma unroll
  for (int mt = 0; mt < 13; ++mt) {
#pragma unroll
    for (int r = 0; r < 4; ++r) {
      int t = mt * 16 + g * 4 + r;
      if (t < TT) atb[(size_t)(t + 4) * CIN + cw] = __float2bfloat16(acc[mt][r] + bpv);
    }
  }
}

// ---------------- K6 (MFMA): dilated conv (3 taps) + residual, two ReLUs ----------------
__global__ __launch_bounds__(256) void k_conv(const bf16* __restrict__ atTp,
    const bf16* __restrict__ xb, const bf16* __restrict__ Wcb, const bf16* __restrict__ Wdb,
    const float* __restrict__ bc, const float* __restrict__ bd, float* __restrict__ out0) {
  int blk = blockIdx.x, b = blk >> 3, og = blk & 7;
  int tid = threadIdx.x, w = tid >> 6, l = tid & 63;
  int lrow = l & 15, g = l >> 4;
  int o0 = og * 64 + w * 16;
  const bf16* wc0 = Wcb + (size_t)(o0 + lrow) * CIN;
  const bf16* wc1 = wc0 + (size_t)COUT * CIN;
  const bf16* wc2 = wc1 + (size_t)COUT * CIN;
  const bf16* wdp = Wdb + (size_t)(o0 + lrow) * CIN;
  const bf16* atb = atTp + (size_t)b * 216 * CIN;
  const bf16* xbb = xb + (size_t)b * 208 * CIN;
  f32x4 accc[13], accr[13];
#pragma unroll
  for (int nt = 0; nt < 13; ++nt) {
    accc[nt] = (f32x4){0.f, 0.f, 0.f, 0.f};
    accr[nt] = (f32x4){0.f, 0.f, 0.f, 0.f};
  }
  for (int kc = 0; kc < 8; ++kc) {
    int kof = kc * 32 + g * 8;
    s16x8 a0 = ld8(&wc0[kof]);
    s16x8 a1 = ld8(&wc1[kof]);
    s16x8 a2 = ld8(&wc2[kof]);
    s16x8 ad = ld8(&wdp[kof]);
#pragma unroll
    for (int nt = 0; nt < 13; ++nt) {
      int tb = nt * 16 + lrow;
      s16x8 b0 = ld8(&atb[(size_t)(tb + 0) * CIN + kof]);
      s16x8 b1 = ld8(&atb[(size_t)(tb + 2) * CIN + kof]);
      s16x8 b2 = ld8(&atb[(size_t)(tb + 4) * CIN + kof]);
      s16x8 bx = ld8(&xbb[(size_t)tb * CIN + kof]);
      accc[nt] = MFMA(a0, b0, accc[nt]);
      accc[nt] = MFMA(a1, b1, accc[nt]);
      accc[nt] = MFMA(a2, b2, accc[nt]);
      accr[nt] = MFMA(ad, bx, accr[nt]);
    }
  }
  f32x4 bcv = *reinterpret_cast<const f32x4*>(&bc[o0 + g * 4]);
  f32x4 bdv = *reinterpret_cast<const f32x4*>(&bd[o0 + g * 4]);
#pragma unroll
  for (int nt = 0; nt < 13; ++nt) {
    int t = nt * 16 + lrow;
    if (t < TT) {
#pragma unroll
      for (int r = 0; r < 4; ++r) {
        int o = o0 + g * 4 + r;
        float conv = fmaxf(accc[nt][r] + bcv[r], 0.f);
        out0[((size_t)b * COUT + o) * TT + t] = fmaxf(conv + accr[nt][r] + bdv[r], 0.f);
      }
    }
  }
}

extern "C" void kernel_launch(void* const* d_in, const int* in_sizes, int n_in,
                              void* d_out, int out_size, void* d_ws, size_t ws_size,
                              hipStream_t stream) {
  const float* x  = (const float*)d_in[0];
  const float* Wq = (const float*)d_in[1];
  const float* bq = (const float*)d_in[2];
  const float* Wk = (const float*)d_in[3];
  const float* bk = (const float*)d_in[4];
  const float* Wv = (const float*)d_in[5];
  const float* bv = (const float*)d_in[6];
  const float* Wp = (const float*)d_in[7];
  const float* bp = (const float*)d_in[8];
  const float* Wc = (const float*)d_in[9];
  const float* bc = (const float*)d_in[10];
  const float* Wd = (const float*)d_in[11];
  const float* bd = (const float*)d_in[12];

  float* out0 = (float*)d_out;
  float* att  = out0 + (size_t)BB * COUT * TT;  // second output, (B,H,T,T)

  char* ws = (char*)d_ws;
  // qo (dead after k_attn) shares space with atTp (written by k_av)
  bf16*  qo   = (bf16*)(ws);                     // 26,214,400 B ([b][t][HK])
  bf16*  atTp = (bf16*)(ws);                     // 14,155,776 B  (B x 216 x 256)
  bf16*  kvo  = (bf16*)(ws + 26214400);          // 26,214,400 B ([b][t][HK])
  bf16*  vpT  = (bf16*)(ws + 52428800);          // 104,857,600 B (BH x 256 x 200)
  bf16*  xb   = (bf16*)(ws + 157286400);         // 13,631,488 B  (B x 208 x 256)
  bf16*  WvpT = (bf16*)(ws + 170917888);         // 1,048,576 B
  float* bvp  = (float*)(ws + 171966464);        // 8,192 B
  bf16*  Wcb  = (bf16*)(ws + 171974656);         // 786,432 B
  bf16*  Wdb  = (bf16*)(ws + 172761088);         // 262,144 B
  bf16*  WqT  = (bf16*)(ws + 173023232);         // 262,144 B
  bf16*  WkT  = (bf16*)(ws + 173285376);         // 262,144 B -> end 173,547,520

  hipLaunchKernelGGL(k_wvp,  dim3(128),      dim3(256), 0, stream, Wv, Wp, bv, WvpT, bvp);
  hipLaunchKernelGGL(k_wc,   dim3(COUT),     dim3(256), 0, stream, Wc, Wd, Wcb, Wdb);
  hipLaunchKernelGGL(k_wqk,  dim3(HK),       dim3(256), 0, stream, Wq, Wk, WqT, WkT);
  hipLaunchKernelGGL(k_xb,   dim3(BB * 7),   dim3(256), 0, stream, x, xb);
  hipLaunchKernelGGL(k_qk,   dim3(BB * 8),   dim3(256), 0, stream, xb, WqT, WkT, bq, bk, qo, kvo);
  hipLaunchKernelGGL(k_attn, dim3(BB * HH),  dim3(256), 0, stream, qo, kvo, att);
  hipLaunchKernelGGL(k_vp,   dim3(BB * 32),  dim3(256), 0, stream, xb, WvpT, bvp, vpT);
  hipLaunchKernelGGL(k_av,   dim3(BB * 4),   dim3(256), 0, stream, att, vpT, bp, atTp);
  hipLaunchKernelGGL(k_conv, dim3(BB * 8),   dim3(256), 0, stream, atTp, xb, Wcb, Wdb, bc, bd, out0);
}

// Round 6
// 790.311 us; speedup vs baseline: 3.6923x; 1.1402x over previous
//
#include <hip/hip_runtime.h>
#include <hip/hip_bf16.h>
#include <math.h>

#define BB 128
#define CIN 256
#define COUT 512
#define TT 200
#define HH 8
#define KD 64
#define HK 512
#define HC 2048

typedef __hip_bfloat16 bf16;
typedef __attribute__((ext_vector_type(8))) short s16x8;
typedef __attribute__((ext_vector_type(4))) short s16x4;
typedef __attribute__((ext_vector_type(4))) float f32x4;

#define MFMA(a, b, c) __builtin_amdgcn_mfma_f32_16x16x32_bf16(a, b, c, 0, 0, 0)

__device__ __forceinline__ short bfs(float f) {
  bf16 h = __float2bfloat16(f);
  return *reinterpret_cast<short*>(&h);
}
__device__ __forceinline__ s16x8 ld8(const bf16* p) {
  return *reinterpret_cast<const s16x8*>(p);
}

// ---------------- K_xb: xb[b][t][c] bf16 <- transpose x (B,C,T) f32; rows 200..207 zero --------
__global__ __launch_bounds__(256) void k_xb(const float* __restrict__ x, bf16* __restrict__ xb) {
  __shared__ float lx[CIN][33];
  int blk = blockIdx.x, b = blk / 7, tt = blk % 7, t0 = tt * 32;
  int tid = threadIdx.x;
  const float* xbp = x + (size_t)b * CIN * TT;
  bf16* xo = xb + (size_t)b * 208 * CIN;
  for (int idx = tid; idx < CIN * 32; idx += 256) {
    int c = idx >> 5, tl = idx & 31, t = t0 + tl;
    lx[c][tl] = (t < TT) ? xbp[(size_t)c * TT + t] : 0.f;
  }
  __syncthreads();
  for (int idx = tid; idx < 32 * 64; idx += 256) {
    int tl = idx >> 6, cs = idx & 63, t = t0 + tl;
    if (t < TT) {
      s16x4 p;
      p[0] = bfs(lx[cs * 4 + 0][tl]); p[1] = bfs(lx[cs * 4 + 1][tl]);
      p[2] = bfs(lx[cs * 4 + 2][tl]); p[3] = bfs(lx[cs * 4 + 3][tl]);
      *reinterpret_cast<s16x4*>(&xo[(size_t)t * CIN + cs * 4]) = p;
    }
  }
  if (tt == 6) {
    s16x4 z = {0, 0, 0, 0};
    for (int idx = tid; idx < 8 * 64; idx += 256) {
      int r = 200 + (idx >> 6), cs = idx & 63;
      *reinterpret_cast<s16x4*>(&xo[(size_t)r * CIN + cs * 4]) = z;
    }
  }
}

// ---------------- K_wc: pack conv/residual weights bf16: Wcb[j][o][i], Wdb[o][i] ----------------
__global__ __launch_bounds__(256) void k_wc(const float* __restrict__ Wc,
    const float* __restrict__ Wd, bf16* __restrict__ Wcb, bf16* __restrict__ Wdb) {
  int o = blockIdx.x, i = threadIdx.x;
  size_t oi = (size_t)o * CIN + i;
#pragma unroll
  for (int j = 0; j < 3; ++j)
    Wcb[(size_t)j * COUT * CIN + oi] = __float2bfloat16(Wc[oi * 3 + j]);
  Wdb[oi] = __float2bfloat16(Wd[oi]);
}

// ---------------- K_wqk: pack WqT[n][ci], WkT[n][ci] bf16 (transpose of (CIN,HK)) -------------
__global__ __launch_bounds__(256) void k_wqk(const float* __restrict__ Wq,
    const float* __restrict__ Wk, bf16* __restrict__ WqT, bf16* __restrict__ WkT) {
  int n = blockIdx.x, ci = threadIdx.x;
  WqT[(size_t)n * CIN + ci] = __float2bfloat16(Wq[(size_t)ci * HK + n]);
  WkT[(size_t)n * CIN + ci] = __float2bfloat16(Wk[(size_t)ci * HK + n]);
}

// ---------------- K1: fold Wv @ Wp_h -> WvpT[h][c][ci] bf16, bvp[h][c] f32 ----------------
__global__ __launch_bounds__(256) void k_wvp(const float* __restrict__ Wv,
    const float* __restrict__ Wp, const float* __restrict__ bv,
    bf16* __restrict__ WvpT, float* __restrict__ bvp) {
  __shared__ __align__(16) float wpl[32][256];
  __shared__ __align__(16) float wvl[17][32];
  int h = blockIdx.x >> 4, ci0 = (blockIdx.x & 15) << 4;
  int c = threadIdx.x;
  float acc[17];
#pragma unroll
  for (int i = 0; i < 17; ++i) acc[i] = 0.f;
  for (int p0 = 0; p0 < CIN; p0 += 32) {
    __syncthreads();
    for (int idx = c; idx < 17 * 32; idx += 256) {
      int pp = idx & 31, cil = idx >> 5;
      wvl[cil][pp] = (cil < 16) ? Wv[(size_t)(ci0 + cil) * HC + h * CIN + p0 + pp]
                                : bv[h * CIN + p0 + pp];
    }
    for (int idx = c; idx < 32 * 256; idx += 256) {
      int cc = idx & 255, pp = idx >> 8;
      wpl[pp][cc] = Wp[(size_t)(h * CIN + p0 + pp) * CIN + cc];
    }
    __syncthreads();
#pragma unroll 4
    for (int pp = 0; pp < 32; ++pp) {
      float w = wpl[pp][c];
#pragma unroll
      for (int i = 0; i < 17; ++i) acc[i] += wvl[i][pp] * w;
    }
  }
  for (int i = 0; i < 16; ++i)
    WvpT[((size_t)h * CIN + c) * CIN + ci0 + i] = __float2bfloat16(acc[i]);
  if (ci0 == 0) bvp[h * CIN + c] = acc[16];
}

// ---------------- K2 (MFMA): q,k = xb @ {WqT,WkT}^T + bias -> bf16 [b][t][HK] ----------------
// XCD swizzle: b = blk&127 so all 8 col-quads of b share an XCD L2 (xb reuse).
__global__ __launch_bounds__(256) void k_qk(const bf16* __restrict__ xb,
    const bf16* __restrict__ WqT, const bf16* __restrict__ WkT,
    const float* __restrict__ bq, const float* __restrict__ bk,
    bf16* __restrict__ qo, bf16* __restrict__ kvo) {
  int blk = blockIdx.x, b = blk & 127, quad = blk >> 7;
  int tid = threadIdx.x, w = tid >> 6, l = tid & 63;
  int lrow = l & 15, g = l >> 4;
  int cw = quad * 64 + w * 16 + lrow;
  const bf16* xbb = xb + (size_t)b * 208 * CIN;
  const bf16* wqt = WqT + (size_t)cw * CIN;
  const bf16* wkt = WkT + (size_t)cw * CIN;
  f32x4 aq[13], ak[13];
#pragma unroll
  for (int mt = 0; mt < 13; ++mt) {
    aq[mt] = (f32x4){0.f, 0.f, 0.f, 0.f};
    ak[mt] = (f32x4){0.f, 0.f, 0.f, 0.f};
  }
  for (int kc = 0; kc < 8; ++kc) {
    int kof = kc * 32 + g * 8;
    s16x8 bqf = ld8(&wqt[kof]);
    s16x8 bkf = ld8(&wkt[kof]);
#pragma unroll
    for (int mt = 0; mt < 13; ++mt) {
      s16x8 afr = ld8(&xbb[(size_t)(mt * 16 + lrow) * CIN + kof]);
      aq[mt] = MFMA(afr, bqf, aq[mt]);
      ak[mt] = MFMA(afr, bkf, ak[mt]);
    }
  }
  float bqv = bq[cw], bkv = bk[cw];
#pragma unroll
  for (int mt = 0; mt < 13; ++mt) {
#pragma unroll
    for (int r = 0; r < 4; ++r) {
      int t = mt * 16 + g * 4 + r;
      if (t < TT) {
        qo[((size_t)b * TT + t) * HK + cw] = __float2bfloat16(aq[mt][r] + bqv);
        kvo[((size_t)b * TT + t) * HK + cw] = __float2bfloat16(ak[mt][r] + bkv);
      }
    }
  }
}

// ---------------- K4 (MFMA): per-(b,h) causal scores + softmax -> att (f32, d_out) ------------
__global__ __launch_bounds__(256) void k_attn(const bf16* __restrict__ qo,
    const bf16* __restrict__ kvo, float* __restrict__ att) {
  int bh = blockIdx.x, b = bh >> 3, h = bh & 7;
  int tid = threadIdx.x, w = tid >> 6, l = tid & 63;
  int lrow = l & 15, g = l >> 4;
  const bf16* qb = qo + (size_t)b * TT * HK + h * KD;
  const bf16* kb = kvo + (size_t)b * TT * HK + h * KD;
  float* ab = att + (size_t)bh * TT * TT;
  for (int mt = w; mt < 13; mt += 4) {
    int ra = mt * 16 + lrow; if (ra > TT - 1) ra = TT - 1;
    s16x8 a0 = ld8(&qb[(size_t)ra * HK + g * 8]);
    s16x8 a1 = ld8(&qb[(size_t)ra * HK + 32 + g * 8]);
    f32x4 sacc[13];
#pragma unroll
    for (int st = 0; st < 13; ++st) sacc[st] = (f32x4){0.f, 0.f, 0.f, 0.f};
#pragma unroll
    for (int st = 0; st < 13; ++st) {
      if (st <= mt) {
        int rb = st * 16 + lrow; if (rb > TT - 1) rb = TT - 1;
        s16x8 b0 = ld8(&kb[(size_t)rb * HK + g * 8]);
        s16x8 b1 = ld8(&kb[(size_t)rb * HK + 32 + g * 8]);
        sacc[st] = MFMA(a0, b0, sacc[st]);
        sacc[st] = MFMA(a1, b1, sacc[st]);
      }
    }
#pragma unroll
    for (int r = 0; r < 4; ++r) {
      int m = mt * 16 + g * 4 + r;
      if (m >= TT) continue;
      float vals[13];
      float mx = -INFINITY;
#pragma unroll
      for (int st = 0; st < 13; ++st) {
        int col = st * 16 + lrow;
        float v = sacc[st][r] * 0.125f;
        vals[st] = (st <= mt && col <= m) ? v : -INFINITY;
        mx = fmaxf(mx, vals[st]);
      }
#pragma unroll
      for (int off = 1; off < 16; off <<= 1) mx = fmaxf(mx, __shfl_xor(mx, off));
      float e[13], sum = 0.f;
#pragma unroll
      for (int st = 0; st < 13; ++st) {
        e[st] = (vals[st] > -INFINITY) ? __expf(vals[st] - mx) : 0.f;
        sum += e[st];
      }
#pragma unroll
      for (int off = 1; off < 16; off <<= 1) sum += __shfl_xor(sum, off);
      float inv = 1.f / sum;
#pragma unroll
      for (int st = 0; st < 13; ++st) {
        int col = st * 16 + lrow;
        if (col < TT) ab[(size_t)m * TT + col] = e[st] * inv;
      }
    }
  }
}

// ---------------- K3 (MFMA): vpT[bh][c][s] = (xb @ WvpT_h^T + bvp), bf16 ----------------
// XCD swizzle: b = blk&127 so the 32 same-b blocks share an XCD L2 (xb reuse).
__global__ __launch_bounds__(256) void k_vp(const bf16* __restrict__ xb,
    const bf16* __restrict__ WvpT, const float* __restrict__ bvp, bf16* __restrict__ vpT) {
  int blk = blockIdx.x;
  int b = blk & 127, r2 = blk >> 7, h = r2 >> 2, q = r2 & 3;
  int tid = threadIdx.x, w = tid >> 6, l = tid & 63;
  int lrow = l & 15, g = l >> 4;
  int cw = q * 64 + w * 16 + lrow;
  const bf16* xbb = xb + (size_t)b * 208 * CIN;
  const bf16* wvt = WvpT + ((size_t)h * CIN + cw) * CIN;
  f32x4 acc[13];
#pragma unroll
  for (int mt = 0; mt < 13; ++mt) acc[mt] = (f32x4){0.f, 0.f, 0.f, 0.f};
  for (int kc = 0; kc < 8; ++kc) {
    int kof = kc * 32 + g * 8;
    s16x8 bfr = ld8(&wvt[kof]);
#pragma unroll
    for (int mt = 0; mt < 13; ++mt) {
      s16x8 afr = ld8(&xbb[(size_t)(mt * 16 + lrow) * CIN + kof]);
      acc[mt] = MFMA(afr, bfr, acc[mt]);
    }
  }
  float bias = bvp[h * CIN + cw];
  bf16* vout = vpT + ((size_t)(b * 8 + h) * CIN + cw) * TT;
#pragma unroll
  for (int mt = 0; mt < 13; ++mt) {
    int s = mt * 16 + g * 4;
    if (s < TT) {
      s16x4 p;
      p[0] = bfs(acc[mt][0] + bias); p[1] = bfs(acc[mt][1] + bias);
      p[2] = bfs(acc[mt][2] + bias); p[3] = bfs(acc[mt][3] + bias);
      *reinterpret_cast<s16x4*>(&vout[s]) = p;
    }
  }
}

// ---------------- K5 (MFMA): atTp[b][t+4][c] = sum_h att_h @ vp_h + bp, bf16 ----------------
// XCD swizzle (b = blk&127): 4 col-quads of b share XCD L2 for the att re-reads.
// Causal fill skip: only rows t >= s0 are staged (rows < s0 are never consumed).
__global__ __launch_bounds__(256) void k_av(const float* __restrict__ att,
    const bf16* __restrict__ vpT, const float* __restrict__ bp, bf16* __restrict__ atTp) {
  __shared__ short lsm[208 * 40];  // up to 208 rows x 32 bf16, 80B padded rows
  int blk = blockIdx.x, b = blk & 127, q = blk >> 7;
  int n0 = q * 64;
  int tid = threadIdx.x, w = tid >> 6, l = tid & 63;
  int lrow = l & 15, g = l >> 4;
  int cw = n0 + w * 16 + lrow;
  bf16* atb = atTp + (size_t)b * 216 * CIN;
  bf16 zb = __float2bfloat16(0.f);
  for (int idx = tid; idx < 12 * 64; idx += 256) {
    int rr = idx >> 6, cc = idx & 63;
    int row = (rr < 4) ? rr : rr + 200;
    atb[(size_t)row * CIN + n0 + cc] = zb;
  }
  f32x4 acc[13];
#pragma unroll
  for (int mt = 0; mt < 13; ++mt) acc[mt] = (f32x4){0.f, 0.f, 0.f, 0.f};
  for (int h = 0; h < HH; ++h) {
    const float* abh = att + (size_t)(b * 8 + h) * TT * TT;
    const bf16* vbh = vpT + (size_t)(b * 8 + h) * CIN * TT;
    for (int s0 = 0; s0 < TT; s0 += 32) {
      int nrows = 208 - s0;  // rows t in [s0, 208) are the only consumers
      __syncthreads();
      for (int idx = tid; idx < nrows * 8; idx += 256) {
        int row = s0 + (idx >> 3), sl = idx & 7;
        float4 v = {0.f, 0.f, 0.f, 0.f};
        if (row < TT && s0 + sl * 4 < TT)
          v = *(const float4*)&abh[(size_t)row * TT + s0 + sl * 4];
        s16x4 p;
        p[0] = bfs(v.x); p[1] = bfs(v.y); p[2] = bfs(v.z); p[3] = bfs(v.w);
        *reinterpret_cast<s16x4*>(&lsm[(row - s0) * 40 + sl * 4]) = p;
      }
      __syncthreads();
      s16x8 bfr = (s0 + g * 8 < TT) ? ld8(&vbh[(size_t)cw * TT + s0 + g * 8])
                                    : (s16x8){0, 0, 0, 0, 0, 0, 0, 0};
#pragma unroll
      for (int mt = 0; mt < 13; ++mt) {
        if ((mt << 4) + 16 > s0) {
          s16x8 afr = *reinterpret_cast<const s16x8*>(&lsm[(mt * 16 + lrow - s0) * 40 + g * 8]);
          acc[mt] = MFMA(afr, bfr, acc[mt]);
        }
      }
    }
  }
  float bpv = bp[cw];
#pragma unroll
  for (int mt = 0; mt < 13; ++mt) {
#pragma unroll
    for (int r = 0; r < 4; ++r) {
      int t = mt * 16 + g * 4 + r;
      if (t < TT) atb[(size_t)(t + 4) * CIN + cw] = __float2bfloat16(acc[mt][r] + bpv);
    }
  }
}

// ---------------- K6 (MFMA): dilated conv (3 taps) + residual, two ReLUs ----------------
// XCD swizzle: b = blk&127 so 8 same-b blocks share XCD L2 (atTp/xb reuse).
__global__ __launch_bounds__(256) void k_conv(const bf16* __restrict__ atTp,
    const bf16* __restrict__ xb, const bf16* __restrict__ Wcb, const bf16* __restrict__ Wdb,
    const float* __restrict__ bc, const float* __restrict__ bd, float* __restrict__ out0) {
  int blk = blockIdx.x, b = blk & 127, og = blk >> 7;
  int tid = threadIdx.x, w = tid >> 6, l = tid & 63;
  int lrow = l & 15, g = l >> 4;
  int o0 = og * 64 + w * 16;
  const bf16* wc0 = Wcb + (size_t)(o0 + lrow) * CIN;
  const bf16* wc1 = wc0 + (size_t)COUT * CIN;
  const bf16* wc2 = wc1 + (size_t)COUT * CIN;
  const bf16* wdp = Wdb + (size_t)(o0 + lrow) * CIN;
  const bf16* atb = atTp + (size_t)b * 216 * CIN;
  const bf16* xbb = xb + (size_t)b * 208 * CIN;
  f32x4 accc[13], accr[13];
#pragma unroll
  for (int nt = 0; nt < 13; ++nt) {
    accc[nt] = (f32x4){0.f, 0.f, 0.f, 0.f};
    accr[nt] = (f32x4){0.f, 0.f, 0.f, 0.f};
  }
  for (int kc = 0; kc < 8; ++kc) {
    int kof = kc * 32 + g * 8;
    s16x8 a0 = ld8(&wc0[kof]);
    s16x8 a1 = ld8(&wc1[kof]);
    s16x8 a2 = ld8(&wc2[kof]);
    s16x8 ad = ld8(&wdp[kof]);
#pragma unroll
    for (int nt = 0; nt < 13; ++nt) {
      int tb = nt * 16 + lrow;
      s16x8 b0 = ld8(&atb[(size_t)(tb + 0) * CIN + kof]);
      s16x8 b1 = ld8(&atb[(size_t)(tb + 2) * CIN + kof]);
      s16x8 b2 = ld8(&atb[(size_t)(tb + 4) * CIN + kof]);
      s16x8 bx = ld8(&xbb[(size_t)tb * CIN + kof]);
      accc[nt] = MFMA(a0, b0, accc[nt]);
      accc[nt] = MFMA(a1, b1, accc[nt]);
      accc[nt] = MFMA(a2, b2, accc[nt]);
      accr[nt] = MFMA(ad, bx, accr[nt]);
    }
  }
  f32x4 bcv = *reinterpret_cast<const f32x4*>(&bc[o0 + g * 4]);
  f32x4 bdv = *reinterpret_cast<const f32x4*>(&bd[o0 + g * 4]);
#pragma unroll
  for (int nt = 0; nt < 13; ++nt) {
    int t = nt * 16 + lrow;
    if (t < TT) {
#pragma unroll
      for (int r = 0; r < 4; ++r) {
        int o = o0 + g * 4 + r;
        float conv = fmaxf(accc[nt][r] + bcv[r], 0.f);
        out0[((size_t)b * COUT + o) * TT + t] = fmaxf(conv + accr[nt][r] + bdv[r], 0.f);
      }
    }
  }
}

extern "C" void kernel_launch(void* const* d_in, const int* in_sizes, int n_in,
                              void* d_out, int out_size, void* d_ws, size_t ws_size,
                              hipStream_t stream) {
  const float* x  = (const float*)d_in[0];
  const float* Wq = (const float*)d_in[1];
  const float* bq = (const float*)d_in[2];
  const float* Wk = (const float*)d_in[3];
  const float* bk = (const float*)d_in[4];
  const float* Wv = (const float*)d_in[5];
  const float* bv = (const float*)d_in[6];
  const float* Wp = (const float*)d_in[7];
  const float* bp = (const float*)d_in[8];
  const float* Wc = (const float*)d_in[9];
  const float* bc = (const float*)d_in[10];
  const float* Wd = (const float*)d_in[11];
  const float* bd = (const float*)d_in[12];

  float* out0 = (float*)d_out;
  float* att  = out0 + (size_t)BB * COUT * TT;  // second output, (B,H,T,T)

  char* ws = (char*)d_ws;
  // qo (dead after k_attn) shares space with atTp (written by k_av)
  bf16*  qo   = (bf16*)(ws);                     // 26,214,400 B ([b][t][HK])
  bf16*  atTp = (bf16*)(ws);                     // 14,155,776 B  (B x 216 x 256)
  bf16*  kvo  = (bf16*)(ws + 26214400);          // 26,214,400 B ([b][t][HK])
  bf16*  vpT  = (bf16*)(ws + 52428800);          // 104,857,600 B (BH x 256 x 200)
  bf16*  xb   = (bf16*)(ws + 157286400);         // 13,631,488 B  (B x 208 x 256)
  bf16*  WvpT = (bf16*)(ws + 170917888);         // 1,048,576 B
  float* bvp  = (float*)(ws + 171966464);        // 8,192 B
  bf16*  Wcb  = (bf16*)(ws + 171974656);         // 786,432 B
  bf16*  Wdb  = (bf16*)(ws + 172761088);         // 262,144 B
  bf16*  WqT  = (bf16*)(ws + 173023232);         // 262,144 B
  bf16*  WkT  = (bf16*)(ws + 173285376);         // 262,144 B -> end 173,547,520

  hipLaunchKernelGGL(k_wvp,  dim3(128),      dim3(256), 0, stream, Wv, Wp, bv, WvpT, bvp);
  hipLaunchKernelGGL(k_wc,   dim3(COUT),     dim3(256), 0, stream, Wc, Wd, Wcb, Wdb);
  hipLaunchKernelGGL(k_wqk,  dim3(HK),       dim3(256), 0, stream, Wq, Wk, WqT, WkT);
  hipLaunchKernelGGL(k_xb,   dim3(BB * 7),   dim3(256), 0, stream, x, xb);
  hipLaunchKernelGGL(k_qk,   dim3(BB * 8),   dim3(256), 0, stream, xb, WqT, WkT, bq, bk, qo, kvo);
  hipLaunchKernelGGL(k_attn, dim3(BB * HH),  dim3(256), 0, stream, qo, kvo, att);
  hipLaunchKernelGGL(k_vp,   dim3(BB * 32),  dim3(256), 0, stream, xb, WvpT, bvp, vpT);
  hipLaunchKernelGGL(k_av,   dim3(BB * 4),   dim3(256), 0, stream, att, vpT, bp, atTp);
  hipLaunchKernelGGL(k_conv, dim3(BB * 8),   dim3(256), 0, stream, atTp, xb, Wcb, Wdb, bc, bd, out0);
}

// Round 7
// 548.765 us; speedup vs baseline: 5.3175x; 1.4402x over previous
//
#include <hip/hip_runtime.h>
#include <hip/hip_bf16.h>
#include <math.h>

#define BB 128
#define CIN 256
#define COUT 512
#define TT 200
#define HH 8
#define KD 64
#define HK 512
#define HC 2048
#define QR 56  // valid t-rows per k_avx block

typedef __hip_bfloat16 bf16;
typedef __attribute__((ext_vector_type(8))) short s16x8;
typedef __attribute__((ext_vector_type(4))) short s16x4;
typedef __attribute__((ext_vector_type(4))) float f32x4;

#define MFMA(a, b, c) __builtin_amdgcn_mfma_f32_16x16x32_bf16(a, b, c, 0, 0, 0)

__device__ __forceinline__ short bfs(float f) {
  bf16 h = __float2bfloat16(f);
  return *reinterpret_cast<short*>(&h);
}
__device__ __forceinline__ s16x8 ld8(const bf16* p) {
  return *reinterpret_cast<const s16x8*>(p);
}

// ---------------- K_xb: xb[b][t][c] (t-major) AND xtb[b][c][t] (c-major, t-pad 224) bf16 ------
__global__ __launch_bounds__(256) void k_xb(const float* __restrict__ x, bf16* __restrict__ xb,
                                            bf16* __restrict__ xtb) {
  __shared__ float lx[CIN][33];
  int blk = blockIdx.x, b = blk / 7, tt = blk % 7, t0 = tt * 32;
  int tid = threadIdx.x;
  const float* xbp = x + (size_t)b * CIN * TT;
  bf16* xo = xb + (size_t)b * 208 * CIN;
  bf16* xto = xtb + (size_t)b * CIN * 224;
  for (int idx = tid; idx < CIN * 32; idx += 256) {
    int c = idx >> 5, tl = idx & 31, t = t0 + tl;
    lx[c][tl] = (t < TT) ? xbp[(size_t)c * TT + t] : 0.f;
  }
  __syncthreads();
  for (int idx = tid; idx < CIN * 32; idx += 256) {
    int c = idx >> 5, tl = idx & 31;
    xto[(size_t)c * 224 + t0 + tl] = __float2bfloat16(lx[c][tl]);  // pad t>=200 -> 0 via lx guard
  }
  for (int idx = tid; idx < 32 * 64; idx += 256) {
    int tl = idx >> 6, cs = idx & 63, t = t0 + tl;
    if (t < TT) {
      s16x4 p;
      p[0] = bfs(lx[cs * 4 + 0][tl]); p[1] = bfs(lx[cs * 4 + 1][tl]);
      p[2] = bfs(lx[cs * 4 + 2][tl]); p[3] = bfs(lx[cs * 4 + 3][tl]);
      *reinterpret_cast<s16x4*>(&xo[(size_t)t * CIN + cs * 4]) = p;
    }
  }
  if (tt == 6) {
    s16x4 z = {0, 0, 0, 0};
    for (int idx = tid; idx < 8 * 64; idx += 256) {
      int r = 200 + (idx >> 6), cs = idx & 63;
      *reinterpret_cast<s16x4*>(&xo[(size_t)r * CIN + cs * 4]) = z;
    }
  }
}

// ---------------- K_wc: pack conv/residual weights bf16: Wcb[j][o][i], Wdb[o][i] ----------------
__global__ __launch_bounds__(256) void k_wc(const float* __restrict__ Wc,
    const float* __restrict__ Wd, bf16* __restrict__ Wcb, bf16* __restrict__ Wdb) {
  int o = blockIdx.x, i = threadIdx.x;
  size_t oi = (size_t)o * CIN + i;
#pragma unroll
  for (int j = 0; j < 3; ++j)
    Wcb[(size_t)j * COUT * CIN + oi] = __float2bfloat16(Wc[oi * 3 + j]);
  Wdb[oi] = __float2bfloat16(Wd[oi]);
}

// ---------------- K_wqk: pack WqT[n][ci], WkT[n][ci] bf16 ----------------
__global__ __launch_bounds__(256) void k_wqk(const float* __restrict__ Wq,
    const float* __restrict__ Wk, bf16* __restrict__ WqT, bf16* __restrict__ WkT) {
  int n = blockIdx.x, ci = threadIdx.x;
  WqT[(size_t)n * CIN + ci] = __float2bfloat16(Wq[(size_t)ci * HK + n]);
  WkT[(size_t)n * CIN + ci] = __float2bfloat16(Wk[(size_t)ci * HK + n]);
}

// ---------------- K1: fold Wv @ Wp_h -> WvpT[h][c][ci] bf16, bvp[h][c] f32 ----------------
__global__ __launch_bounds__(256) void k_wvp(const float* __restrict__ Wv,
    const float* __restrict__ Wp, const float* __restrict__ bv,
    bf16* __restrict__ WvpT, float* __restrict__ bvp) {
  __shared__ __align__(16) float wpl[32][256];
  __shared__ __align__(16) float wvl[17][32];
  int h = blockIdx.x >> 4, ci0 = (blockIdx.x & 15) << 4;
  int c = threadIdx.x;
  float acc[17];
#pragma unroll
  for (int i = 0; i < 17; ++i) acc[i] = 0.f;
  for (int p0 = 0; p0 < CIN; p0 += 32) {
    __syncthreads();
    for (int idx = c; idx < 17 * 32; idx += 256) {
      int pp = idx & 31, cil = idx >> 5;
      wvl[cil][pp] = (cil < 16) ? Wv[(size_t)(ci0 + cil) * HC + h * CIN + p0 + pp]
                                : bv[h * CIN + p0 + pp];
    }
    for (int idx = c; idx < 32 * 256; idx += 256) {
      int cc = idx & 255, pp = idx >> 8;
      wpl[pp][cc] = Wp[(size_t)(h * CIN + p0 + pp) * CIN + cc];
    }
    __syncthreads();
#pragma unroll 4
    for (int pp = 0; pp < 32; ++pp) {
      float w = wpl[pp][c];
#pragma unroll
      for (int i = 0; i < 17; ++i) acc[i] += wvl[i][pp] * w;
    }
  }
  for (int i = 0; i < 16; ++i)
    WvpT[((size_t)h * CIN + c) * CIN + ci0 + i] = __float2bfloat16(acc[i]);
  if (ci0 == 0) bvp[h * CIN + c] = acc[16];
}

// ---------------- K2 (MFMA): q,k = xb @ {WqT,WkT}^T + bias -> bf16 [b][t][HK] ----------------
__global__ __launch_bounds__(256) void k_qk(const bf16* __restrict__ xb,
    const bf16* __restrict__ WqT, const bf16* __restrict__ WkT,
    const float* __restrict__ bq, const float* __restrict__ bk,
    bf16* __restrict__ qo, bf16* __restrict__ kvo) {
  int blk = blockIdx.x, b = blk & 127, quad = blk >> 7;
  int tid = threadIdx.x, w = tid >> 6, l = tid & 63;
  int lrow = l & 15, g = l >> 4;
  int cw = quad * 64 + w * 16 + lrow;
  const bf16* xbb = xb + (size_t)b * 208 * CIN;
  const bf16* wqt = WqT + (size_t)cw * CIN;
  const bf16* wkt = WkT + (size_t)cw * CIN;
  f32x4 aq[13], ak[13];
#pragma unroll
  for (int mt = 0; mt < 13; ++mt) {
    aq[mt] = (f32x4){0.f, 0.f, 0.f, 0.f};
    ak[mt] = (f32x4){0.f, 0.f, 0.f, 0.f};
  }
  for (int kc = 0; kc < 8; ++kc) {
    int kof = kc * 32 + g * 8;
    s16x8 bqf = ld8(&wqt[kof]);
    s16x8 bkf = ld8(&wkt[kof]);
#pragma unroll
    for (int mt = 0; mt < 13; ++mt) {
      s16x8 afr = ld8(&xbb[(size_t)(mt * 16 + lrow) * CIN + kof]);
      aq[mt] = MFMA(afr, bqf, aq[mt]);
      ak[mt] = MFMA(afr, bkf, ak[mt]);
    }
  }
  float bqv = bq[cw], bkv = bk[cw];
#pragma unroll
  for (int mt = 0; mt < 13; ++mt) {
#pragma unroll
    for (int r = 0; r < 4; ++r) {
      int t = mt * 16 + g * 4 + r;
      if (t < TT) {
        qo[((size_t)b * TT + t) * HK + cw] = __float2bfloat16(aq[mt][r] + bqv);
        kvo[((size_t)b * TT + t) * HK + cw] = __float2bfloat16(ak[mt][r] + bkv);
      }
    }
  }
}

// ---------------- K4 (MFMA): per-(b,h) causal scores + softmax -> att (f32, d_out) ------------
__global__ __launch_bounds__(256) void k_attn(const bf16* __restrict__ qo,
    const bf16* __restrict__ kvo, float* __restrict__ att) {
  int bh = blockIdx.x, b = bh >> 3, h = bh & 7;
  int tid = threadIdx.x, w = tid >> 6, l = tid & 63;
  int lrow = l & 15, g = l >> 4;
  const bf16* qb = qo + (size_t)b * TT * HK + h * KD;
  const bf16* kb = kvo + (size_t)b * TT * HK + h * KD;
  float* ab = att + (size_t)bh * TT * TT;
  for (int mt = w; mt < 13; mt += 4) {
    int ra = mt * 16 + lrow; if (ra > TT - 1) ra = TT - 1;
    s16x8 a0 = ld8(&qb[(size_t)ra * HK + g * 8]);
    s16x8 a1 = ld8(&qb[(size_t)ra * HK + 32 + g * 8]);
    f32x4 sacc[13];
#pragma unroll
    for (int st = 0; st < 13; ++st) sacc[st] = (f32x4){0.f, 0.f, 0.f, 0.f};
#pragma unroll
    for (int st = 0; st < 13; ++st) {
      if (st <= mt) {
        int rb = st * 16 + lrow; if (rb > TT - 1) rb = TT - 1;
        s16x8 b0 = ld8(&kb[(size_t)rb * HK + g * 8]);
        s16x8 b1 = ld8(&kb[(size_t)rb * HK + 32 + g * 8]);
        sacc[st] = MFMA(a0, b0, sacc[st]);
        sacc[st] = MFMA(a1, b1, sacc[st]);
      }
    }
#pragma unroll
    for (int r = 0; r < 4; ++r) {
      int m = mt * 16 + g * 4 + r;
      if (m >= TT) continue;
      float vals[13];
      float mx = -INFINITY;
#pragma unroll
      for (int st = 0; st < 13; ++st) {
        int col = st * 16 + lrow;
        float v = sacc[st][r] * 0.125f;
        vals[st] = (st <= mt && col <= m) ? v : -INFINITY;
        mx = fmaxf(mx, vals[st]);
      }
#pragma unroll
      for (int off = 1; off < 16; off <<= 1) mx = fmaxf(mx, __shfl_xor(mx, off));
      float e[13], sum = 0.f;
#pragma unroll
      for (int st = 0; st < 13; ++st) {
        e[st] = (vals[st] > -INFINITY) ? __expf(vals[st] - mx) : 0.f;
        sum += e[st];
      }
#pragma unroll
      for (int off = 1; off < 16; off <<= 1) sum += __shfl_xor(sum, off);
      float inv = 1.f / sum;
#pragma unroll
      for (int st = 0; st < 13; ++st) {
        int col = st * 16 + lrow;
        if (col < TT) ab[(size_t)m * TT + col] = e[st] * inv;
      }
    }
  }
}

// ---------------- K5 (MFMA, fused): atTp[t+4][c] = sum_h (att_h @ x^T) @ WvpT_h + biases -------
// Per block: (b, t-quarter of 56 rows). Stage1: y[ci][t] tile via A=xtb(ci-rows), B=att(t-rows,
// staged bf16 in LDS) -> y written to LDS [t][ci]. Stage2: acc2 += y @ WvpT_h. Causal s-tile skip.
__global__ __launch_bounds__(256) void k_avx(const float* __restrict__ att,
    const bf16* __restrict__ xtb, const bf16* __restrict__ WvpT,
    const float* __restrict__ bvp, const float* __restrict__ bp,
    bf16* __restrict__ atTp) {
  __shared__ short lsm[64 * 40];   // att tile: 64 t-rows x 32 s bf16 (40-short stride)
  __shared__ short yl[64 * 260];   // y: 64 t-rows x 256 ci bf16 (260-short stride, 8B-aligned)
  int blk = blockIdx.x, b = blk & 127, q = blk >> 7;
  int t0 = q * QR;
  int tid = threadIdx.x, w = tid >> 6, l = tid & 63;
  int lrow = l & 15, g = l >> 4;
  bf16* atb = atTp + (size_t)b * 216 * CIN;
  bf16 zb = __float2bfloat16(0.f);
  if (q == 0) { for (int idx = tid; idx < 4 * CIN; idx += 256) atb[idx] = zb; }
  if (q == 3) { for (int idx = tid; idx < 8 * CIN; idx += 256) atb[204 * CIN + idx] = zb; }
  const bf16* xr = xtb + (size_t)b * CIN * 224;
  f32x4 acc2[4][4];
#pragma unroll
  for (int mt = 0; mt < 4; ++mt)
#pragma unroll
    for (int nt = 0; nt < 4; ++nt) acc2[mt][nt] = (f32x4){0.f, 0.f, 0.f, 0.f};
  for (int h = 0; h < HH; ++h) {
    const float* abh = att + (size_t)(b * HH + h) * TT * TT;
    f32x4 acc1[4][4];
#pragma unroll
    for (int mc = 0; mc < 4; ++mc)
#pragma unroll
      for (int nt = 0; nt < 4; ++nt) acc1[mc][nt] = (f32x4){0.f, 0.f, 0.f, 0.f};
    for (int s0 = 0; s0 < TT && s0 <= t0 + QR - 1; s0 += 32) {
      __syncthreads();
      for (int idx = tid; idx < 64 * 8; idx += 256) {
        int rr = idx >> 3, sl = idx & 7;
        int ra = t0 + rr; if (ra > TT - 1) ra = TT - 1;
        float4 v = {0.f, 0.f, 0.f, 0.f};
        if (s0 + sl * 4 < TT) v = *(const float4*)&abh[(size_t)ra * TT + s0 + sl * 4];
        s16x4 p;
        p[0] = bfs(v.x); p[1] = bfs(v.y); p[2] = bfs(v.z); p[3] = bfs(v.w);
        *reinterpret_cast<s16x4*>(&lsm[rr * 40 + sl * 4]) = p;
      }
      __syncthreads();
      s16x8 bat[4];
#pragma unroll
      for (int nt = 0; nt < 4; ++nt)
        bat[nt] = *reinterpret_cast<const s16x8*>(&lsm[(nt * 16 + lrow) * 40 + g * 8]);
#pragma unroll
      for (int mc = 0; mc < 4; ++mc) {
        s16x8 af = ld8(&xr[(size_t)(w * 64 + mc * 16 + lrow) * 224 + s0 + g * 8]);
#pragma unroll
        for (int nt = 0; nt < 4; ++nt)
          acc1[mc][nt] = MFMA(af, bat[nt], acc1[mc][nt]);
      }
    }
    __syncthreads();  // prior stage2 yl reads complete (also covered by s-loop barriers)
#pragma unroll
    for (int mc = 0; mc < 4; ++mc)
#pragma unroll
      for (int nt = 0; nt < 4; ++nt) {
        s16x4 p;
        p[0] = bfs(acc1[mc][nt][0]); p[1] = bfs(acc1[mc][nt][1]);
        p[2] = bfs(acc1[mc][nt][2]); p[3] = bfs(acc1[mc][nt][3]);
        *reinterpret_cast<s16x4*>(&yl[(nt * 16 + lrow) * 260 + w * 64 + mc * 16 + g * 4]) = p;
      }
    __syncthreads();
    const bf16* wv = WvpT + (size_t)h * CIN * CIN;
#pragma unroll
    for (int kc = 0; kc < 8; ++kc) {
      int kof = kc * 32 + g * 8;
      s16x8 bw[4];
#pragma unroll
      for (int nt = 0; nt < 4; ++nt)
        bw[nt] = ld8(&wv[(size_t)(w * 64 + nt * 16 + lrow) * CIN + kof]);
#pragma unroll
      for (int mt = 0; mt < 4; ++mt) {
        s16x4 alo = *reinterpret_cast<const s16x4*>(&yl[(mt * 16 + lrow) * 260 + kof]);
        s16x4 ahi = *reinterpret_cast<const s16x4*>(&yl[(mt * 16 + lrow) * 260 + kof + 4]);
        s16x8 ay;
        ay[0] = alo[0]; ay[1] = alo[1]; ay[2] = alo[2]; ay[3] = alo[3];
        ay[4] = ahi[0]; ay[5] = ahi[1]; ay[6] = ahi[2]; ay[7] = ahi[3];
#pragma unroll
        for (int nt = 0; nt < 4; ++nt)
          acc2[mt][nt] = MFMA(ay, bw[nt], acc2[mt][nt]);
      }
    }
  }
  int climit = TT - t0; if (climit > QR) climit = QR;
#pragma unroll
  for (int nt = 0; nt < 4; ++nt) {
    int c = w * 64 + nt * 16 + lrow;
    float bsum = bp[c];
#pragma unroll
    for (int h = 0; h < HH; ++h) bsum += bvp[h * CIN + c];
#pragma unroll
    for (int mt = 0; mt < 4; ++mt) {
#pragma unroll
      for (int r = 0; r < 4; ++r) {
        int tloc = mt * 16 + g * 4 + r;
        if (tloc < climit)
          atb[(size_t)(t0 + tloc + 4) * CIN + c] = __float2bfloat16(acc2[mt][nt][r] + bsum);
      }
    }
  }
}

// ---------------- K6 (MFMA): dilated conv (3 taps) + residual, two ReLUs ----------------
__global__ __launch_bounds__(256) void k_conv(const bf16* __restrict__ atTp,
    const bf16* __restrict__ xb, const bf16* __restrict__ Wcb, const bf16* __restrict__ Wdb,
    const float* __restrict__ bc, const float* __restrict__ bd, float* __restrict__ out0) {
  int blk = blockIdx.x, b = blk & 127, og = blk >> 7;
  int tid = threadIdx.x, w = tid >> 6, l = tid & 63;
  int lrow = l & 15, g = l >> 4;
  int o0 = og * 64 + w * 16;
  const bf16* wc0 = Wcb + (size_t)(o0 + lrow) * CIN;
  const bf16* wc1 = wc0 + (size_t)COUT * CIN;
  const bf16* wc2 = wc1 + (size_t)COUT * CIN;
  const bf16* wdp = Wdb + (size_t)(o0 + lrow) * CIN;
  const bf16* atb = atTp + (size_t)b * 216 * CIN;
  const bf16* xbb = xb + (size_t)b * 208 * CIN;
  f32x4 accc[13], accr[13];
#pragma unroll
  for (int nt = 0; nt < 13; ++nt) {
    accc[nt] = (f32x4){0.f, 0.f, 0.f, 0.f};
    accr[nt] = (f32x4){0.f, 0.f, 0.f, 0.f};
  }
  for (int kc = 0; kc < 8; ++kc) {
    int kof = kc * 32 + g * 8;
    s16x8 a0 = ld8(&wc0[kof]);
    s16x8 a1 = ld8(&wc1[kof]);
    s16x8 a2 = ld8(&wc2[kof]);
    s16x8 ad = ld8(&wdp[kof]);
#pragma unroll
    for (int nt = 0; nt < 13; ++nt) {
      int tb = nt * 16 + lrow;
      s16x8 b0 = ld8(&atb[(size_t)(tb + 0) * CIN + kof]);
      s16x8 b1 = ld8(&atb[(size_t)(tb + 2) * CIN + kof]);
      s16x8 b2 = ld8(&atb[(size_t)(tb + 4) * CIN + kof]);
      s16x8 bx = ld8(&xbb[(size_t)tb * CIN + kof]);
      accc[nt] = MFMA(a0, b0, accc[nt]);
      accc[nt] = MFMA(a1, b1, accc[nt]);
      accc[nt] = MFMA(a2, b2, accc[nt]);
      accr[nt] = MFMA(ad, bx, accr[nt]);
    }
  }
  f32x4 bcv = *reinterpret_cast<const f32x4*>(&bc[o0 + g * 4]);
  f32x4 bdv = *reinterpret_cast<const f32x4*>(&bd[o0 + g * 4]);
#pragma unroll
  for (int nt = 0; nt < 13; ++nt) {
    int t = nt * 16 + lrow;
    if (t < TT) {
#pragma unroll
      for (int r = 0; r < 4; ++r) {
        int o = o0 + g * 4 + r;
        float conv = fmaxf(accc[nt][r] + bcv[r], 0.f);
        out0[((size_t)b * COUT + o) * TT + t] = fmaxf(conv + accr[nt][r] + bdv[r], 0.f);
      }
    }
  }
}

extern "C" void kernel_launch(void* const* d_in, const int* in_sizes, int n_in,
                              void* d_out, int out_size, void* d_ws, size_t ws_size,
                              hipStream_t stream) {
  const float* x  = (const float*)d_in[0];
  const float* Wq = (const float*)d_in[1];
  const float* bq = (const float*)d_in[2];
  const float* Wk = (const float*)d_in[3];
  const float* bk = (const float*)d_in[4];
  const float* Wv = (const float*)d_in[5];
  const float* bv = (const float*)d_in[6];
  const float* Wp = (const float*)d_in[7];
  const float* bp = (const float*)d_in[8];
  const float* Wc = (const float*)d_in[9];
  const float* bc = (const float*)d_in[10];
  const float* Wd = (const float*)d_in[11];
  const float* bd = (const float*)d_in[12];

  float* out0 = (float*)d_out;
  float* att  = out0 + (size_t)BB * COUT * TT;  // second output, (B,H,T,T)

  char* ws = (char*)d_ws;
  // qo (dead after k_attn) shares space with atTp (written by k_avx)
  bf16*  qo   = (bf16*)(ws);                     // 26,214,400 B ([b][t][HK])
  bf16*  atTp = (bf16*)(ws);                     // 14,155,776 B  (B x 216 x 256)
  bf16*  kvo  = (bf16*)(ws + 26214400);          // 26,214,400 B ([b][t][HK])
  bf16*  xtb  = (bf16*)(ws + 52428800);          // 14,680,064 B  (B x 256 x 224)
  bf16*  xb   = (bf16*)(ws + 157286400);         // 13,631,488 B  (B x 208 x 256)
  bf16*  WvpT = (bf16*)(ws + 170917888);         // 1,048,576 B
  float* bvp  = (float*)(ws + 171966464);        // 8,192 B
  bf16*  Wcb  = (bf16*)(ws + 171974656);         // 786,432 B
  bf16*  Wdb  = (bf16*)(ws + 172761088);         // 262,144 B
  bf16*  WqT  = (bf16*)(ws + 173023232);         // 262,144 B
  bf16*  WkT  = (bf16*)(ws + 173285376);         // 262,144 B -> end 173,547,520

  hipLaunchKernelGGL(k_wvp,  dim3(128),      dim3(256), 0, stream, Wv, Wp, bv, WvpT, bvp);
  hipLaunchKernelGGL(k_wc,   dim3(COUT),     dim3(256), 0, stream, Wc, Wd, Wcb, Wdb);
  hipLaunchKernelGGL(k_wqk,  dim3(HK),       dim3(256), 0, stream, Wq, Wk, WqT, WkT);
  hipLaunchKernelGGL(k_xb,   dim3(BB * 7),   dim3(256), 0, stream, x, xb, xtb);
  hipLaunchKernelGGL(k_qk,   dim3(BB * 8),   dim3(256), 0, stream, xb, WqT, WkT, bq, bk, qo, kvo);
  hipLaunchKernelGGL(k_attn, dim3(BB * HH),  dim3(256), 0, stream, qo, kvo, att);
  hipLaunchKernelGGL(k_avx,  dim3(BB * 4),   dim3(256), 0, stream, att, xtb, WvpT, bvp, bp, atTp);
  hipLaunchKernelGGL(k_conv, dim3(BB * 8),   dim3(256), 0, stream, atTp, xb, Wcb, Wdb, bc, bd, out0);
}